// Round 3
// baseline (650.462 us; speedup 1.0000x reference)
//
#include <hip/hip_runtime.h>
#include <math.h>

constexpr int BB   = 2;
constexpr int CC   = 64;
constexpr int HH   = 128;
constexpr int WW   = 128;
constexpr int OO   = 64;
constexpr int HWSZ = HH * WW;    // 16384
constexpr int HOWO = 16384;
constexpr int OMC  = 27;

// ---------------------------------------------------------------------------
// Prep: wt_om [9][64][28] (27 padded to 28), wt_dcn [9][64][64]
// ---------------------------------------------------------------------------
__global__ __launch_bounds__(256) void prep_transpose(
    const float* __restrict__ w_dcn, const float* __restrict__ w_om,
    float* __restrict__ wt_dcn, float* __restrict__ wt_om)
{
    int idx = blockIdx.x * 256 + threadIdx.x;
    if (idx < 9 * 64 * 64) {
        int o  = idx & 63;
        int c  = (idx >> 6) & 63;
        int kk = idx >> 12;
        wt_dcn[idx] = w_dcn[(o * CC + c) * 9 + kk];
    }
    if (idx < 9 * 64 * 28) {
        int o    = idx % 28;
        int rest = idx / 28;
        int c    = rest & 63;
        int kk   = rest >> 6;
        wt_om[idx] = (o < OMC) ? w_om[(o * CC + c) * 9 + kk] : 0.f;
    }
}

__device__ __forceinline__ void bilinear_params(
    float oy, float ox, float m, int ho, int wo, int ky, int kx,
    float& w00, float& w01, float& w10, float& w11,
    int& i00, int& i01, int& i10, int& i11)
{
    const float yf = (float)(ho + ky - 1) + oy;
    const float xf = (float)(wo + kx - 1) + ox;
    const float y0 = floorf(yf), x0 = floorf(xf);
    const float ly = yf - y0, lx = xf - x0;
    const float hy = 1.f - ly, hx = 1.f - lx;
    const int iy0 = (int)y0, ix0 = (int)x0;
    const int iy1 = iy0 + 1, ix1 = ix0 + 1;
    const bool vy0 = (unsigned)iy0 < (unsigned)HH;
    const bool vy1 = (unsigned)iy1 < (unsigned)HH;
    const bool vx0 = (unsigned)ix0 < (unsigned)WW;
    const bool vx1 = (unsigned)ix1 < (unsigned)WW;
    w00 = (vy0 && vx0) ? hy * hx * m : 0.f;
    w01 = (vy0 && vx1) ? hy * lx * m : 0.f;
    w10 = (vy1 && vx0) ? ly * hx * m : 0.f;
    w11 = (vy1 && vx1) ? ly * lx * m : 0.f;
    const int cy0 = min(max(iy0, 0), HH - 1), cy1 = min(max(iy1, 0), HH - 1);
    const int cx0 = min(max(ix0, 0), WW - 1), cx1 = min(max(ix1, 0), WW - 1);
    i00 = cy0 * WW + cx0; i01 = cy0 * WW + cx1;
    i10 = cy1 * WW + cx0; i11 = cy1 * WW + cx1;
}

// ---------------------------------------------------------------------------
// Fused kernel. Block = 256 threads = 32 pixels x 8 groups.
// Part A: 27-ch offset conv, partial over 8 input ch/thread -> LDS reduce.
// Part B: per kk: gather v once per (c,pix) into LDS (double-buffered,
//         loads issued before the GEMM of the previous kk = T14), then
//         GEMM: thread (pix, ocg8) accumulates acc[8] over all 64 c.
// ---------------------------------------------------------------------------
__global__ __launch_bounds__(256, 4) void fused_dcn_kernel(
    const float* __restrict__ xo,    // input_offset
    const float* __restrict__ xr,    // input_real
    const float* __restrict__ wtom,  // [9][64][28]
    const float* __restrict__ bom,   // [27]
    const float* __restrict__ wtd,   // [9][64][64]
    const float* __restrict__ bd,    // [64]
    float* __restrict__ out,         // [B][64][HoWo]
    float* __restrict__ off_out)     // [B][18][HoWo]
{
    __shared__ float lds_om[8][32][29];   // 29696 B; reused for v-buffers
    __shared__ float lds_offm[32][29];    // [pix][0..17]=offset, [18..26]=mask

    const int tid  = threadIdx.x;
    const int pixl = tid & 31;
    const int grp  = tid >> 5;                 // c-group (A/gather), oc-group (GEMM)
    const int pixg = blockIdx.x * 32 + pixl;
    const int b    = pixg >> 14;
    const int p    = pixg & 16383;
    const int p0   = (blockIdx.x * 32) & 16383;
    const int ho   = p >> 7, wo = p & 127;

    // ---------------- Part A: offset/mask conv (partial over 8 channels)
    {
        float oma[28];
#pragma unroll
        for (int j = 0; j < 28; ++j) oma[j] = 0.f;
        const float* xb = xo + (size_t)b * CC * HWSZ;
#pragma unroll 2
        for (int i = 0; i < 8; ++i) {
            const int c = grp * 8 + i;
            const float* xc = xb + c * HWSZ;
            float t[9];
#pragma unroll
            for (int kh = 0; kh < 3; ++kh) {
                const int ih = ho + kh - 1;
                const bool rv = (unsigned)ih < (unsigned)HH;
#pragma unroll
                for (int kw = 0; kw < 3; ++kw) {
                    const int iw = wo + kw - 1;
                    t[kh * 3 + kw] =
                        (rv && (unsigned)iw < (unsigned)WW) ? xc[ih * WW + iw] : 0.f;
                }
            }
#pragma unroll
            for (int kk = 0; kk < 9; ++kk) {
                const float tv = t[kk];
                const float4* wr = (const float4*)(wtom + ((kk << 6) + c) * 28);
#pragma unroll
                for (int q = 0; q < 7; ++q) {
                    const float4 wv = wr[q];
                    oma[q * 4 + 0] += tv * wv.x;
                    oma[q * 4 + 1] += tv * wv.y;
                    oma[q * 4 + 2] += tv * wv.z;
                    oma[q * 4 + 3] += tv * wv.w;
                }
            }
        }
#pragma unroll
        for (int j = 0; j < 28; ++j) lds_om[grp][pixl][j] = oma[j];
    }
    __syncthreads();

#pragma unroll
    for (int it = 0; it < 4; ++it) {
        const int idx = it * 256 + tid;
        if (idx < 32 * 27) {
            const int pp = idx & 31;
            const int o  = idx >> 5;
            float s = bom[o];
#pragma unroll
            for (int g = 0; g < 8; ++g) s += lds_om[g][pp][o];
            if (o < 18) {
                off_out[(b * 18 + o) * HOWO + p0 + pp] = s;
                lds_offm[pp][o] = s;
            } else {
                lds_offm[pp][o] = 1.f / (1.f + expf(-s));
            }
        }
    }
    __syncthreads();

    // ---------------- Part B
    float* vbuf0 = &lds_om[0][0][0];           // [64][33] = 8448 B
    float* vbuf1 = vbuf0 + 64 * 33;            // second buffer (fits in lds_om)

    const float* xrb = xr + (size_t)b * CC * HWSZ;
    float acc[8];
#pragma unroll
    for (int j = 0; j < 8; ++j) acc[j] = 0.f;

    // prologue: full gather for kk=0 into vbuf0
    {
        float w00, w01, w10, w11; int i00, i01, i10, i11;
        bilinear_params(lds_offm[pixl][0], lds_offm[pixl][1], lds_offm[pixl][18],
                        ho, wo, 0, 0, w00, w01, w10, w11, i00, i01, i10, i11);
#pragma unroll
        for (int i = 0; i < 8; ++i) {
            const int c = grp * 8 + i;
            const float* xc = xrb + c * HWSZ;
            const float v = w00 * xc[i00] + w01 * xc[i01] +
                            w10 * xc[i10] + w11 * xc[i11];
            vbuf0[c * 33 + pixl] = v;
        }
    }

    for (int kk = 0; kk < 9; ++kk) {
        __syncthreads();
        float* cur = (kk & 1) ? vbuf1 : vbuf0;
        float* nxt = (kk & 1) ? vbuf0 : vbuf1;

        // T14: issue next-kk gather loads BEFORE the GEMM
        float r00[8], r01[8], r10[8], r11[8];
        float nw00 = 0.f, nw01 = 0.f, nw10 = 0.f, nw11 = 0.f;
        if (kk < 8) {
            const int nk = kk + 1;
            const int ky = nk / 3, kx = nk - ky * 3;
            int i00, i01, i10, i11;
            bilinear_params(lds_offm[pixl][2 * nk], lds_offm[pixl][2 * nk + 1],
                            lds_offm[pixl][18 + nk], ho, wo, ky, kx,
                            nw00, nw01, nw10, nw11, i00, i01, i10, i11);
#pragma unroll
            for (int i = 0; i < 8; ++i) {
                const int c = grp * 8 + i;
                const float* xc = xrb + c * HWSZ;
                r00[i] = xc[i00];
                r01[i] = xc[i01];
                r10[i] = xc[i10];
                r11[i] = xc[i11];
            }
        }

        // GEMM: acc[0..7] over all 64 channels from LDS
        const float* wk = wtd + (kk << 12) + (grp << 3);
#pragma unroll 8
        for (int c = 0; c < 64; ++c) {
            const float v = cur[c * 33 + pixl];
            const float4* wr = (const float4*)(wk + (c << 6));
            const float4 wv0 = wr[0];
            const float4 wv1 = wr[1];
            acc[0] += v * wv0.x;
            acc[1] += v * wv0.y;
            acc[2] += v * wv0.z;
            acc[3] += v * wv0.w;
            acc[4] += v * wv1.x;
            acc[5] += v * wv1.y;
            acc[6] += v * wv1.z;
            acc[7] += v * wv1.w;
        }

        // combine + write next-kk v into the other buffer
        if (kk < 8) {
#pragma unroll
            for (int i = 0; i < 8; ++i) {
                const int c = grp * 8 + i;
                const float v = nw00 * r00[i] + nw01 * r01[i] +
                                nw10 * r10[i] + nw11 * r11[i];
                nxt[c * 33 + pixl] = v;
            }
        }
    }

    // ---------------- store
#pragma unroll
    for (int q = 0; q < 8; ++q) {
        const int oc = grp * 8 + q;
        out[((size_t)(b * OO + oc)) * HOWO + p0 + pixl] = acc[q] + bd[oc];
    }
}

// ---------------------------------------------------------------------------
// Slow fallback (round-0, verified): used only if ws_size is too small.
// ---------------------------------------------------------------------------
__global__ __launch_bounds__(256) void conv_om_slow(
    const float* __restrict__ x, const float* __restrict__ w,
    const float* __restrict__ bias, float* __restrict__ off_out)
{
    const int xid = blockIdx.x;
    const int b   = xid >> 6;
    const int p   = ((xid & 63) << 8) + threadIdx.x;
    const int ho  = p >> 7, wo = p & 127;
    const int oc0 = blockIdx.y << 4;

    float acc[16];
#pragma unroll
    for (int j = 0; j < 16; ++j) {
        const int oc = oc0 + j;
        acc[j] = (oc < OMC) ? bias[oc] : 0.f;
    }
    const float* xb = x + (size_t)b * CC * HWSZ;
    for (int c = 0; c < CC; ++c) {
        const float* xc = xb + c * HWSZ;
        float t[9];
#pragma unroll
        for (int kh = 0; kh < 3; ++kh) {
            const int ih = ho + kh - 1;
            const bool rv = (unsigned)ih < (unsigned)HH;
#pragma unroll
            for (int kw = 0; kw < 3; ++kw) {
                const int iw = wo + kw - 1;
                t[kh * 3 + kw] =
                    (rv && (unsigned)iw < (unsigned)WW) ? xc[ih * WW + iw] : 0.f;
            }
        }
#pragma unroll
        for (int j = 0; j < 16; ++j) {
            const int oc = oc0 + j;
            if (oc < OMC) {
                const float* wj = w + (size_t)(oc * CC + c) * 9;
                float s = 0.f;
#pragma unroll
                for (int kk = 0; kk < 9; ++kk) s += t[kk] * wj[kk];
                acc[j] += s;
            }
        }
    }
#pragma unroll
    for (int j = 0; j < 16; ++j) {
        const int oc = oc0 + j;
        if (oc < 18) off_out[(b * 18 + oc) * HOWO + p] = acc[j];
    }
}

__global__ __launch_bounds__(256) void dcn_slow(
    const float* __restrict__ xr, const float* __restrict__ off,
    const float* __restrict__ wd, const float* __restrict__ bd,
    float* __restrict__ out, const float* __restrict__ xo,
    const float* __restrict__ wom, const float* __restrict__ bom)
{
    const int xid = blockIdx.x;
    const int b   = xid >> 6;
    const int p   = ((xid & 63) << 8) + threadIdx.x;
    const int ho  = p >> 7, wo = p & 127;
    const int o0  = blockIdx.y << 4;

    float acc[16];
#pragma unroll
    for (int j = 0; j < 16; ++j) acc[j] = bd[o0 + j];
    const float* xb = xr + (size_t)b * CC * HWSZ;

    for (int kk = 0; kk < 9; ++kk) {
        const float oy = off[(b * 18 + 2 * kk) * HOWO + p];
        const float ox = off[(b * 18 + 2 * kk + 1) * HOWO + p];
        float a = bom[18 + kk];
        const float* xob = xo + (size_t)b * CC * HWSZ;
        for (int c = 0; c < CC; ++c) {
            const float* xc2 = xob + c * HWSZ;
            const float* wj  = wom + (size_t)((18 + kk) * CC + c) * 9;
#pragma unroll
            for (int kh = 0; kh < 3; ++kh) {
                const int ih = ho + kh - 1;
                if ((unsigned)ih < (unsigned)HH) {
#pragma unroll
                    for (int kw = 0; kw < 3; ++kw) {
                        const int iw = wo + kw - 1;
                        if ((unsigned)iw < (unsigned)WW)
                            a += xc2[ih * WW + iw] * wj[kh * 3 + kw];
                    }
                }
            }
        }
        const float m = 1.f / (1.f + expf(-a));

        const int ky = kk / 3, kx = kk - ky * 3;
        float w00, w01, w10, w11; int i00, i01, i10, i11;
        bilinear_params(oy, ox, m, ho, wo, ky, kx,
                        w00, w01, w10, w11, i00, i01, i10, i11);

#pragma unroll 4
        for (int c = 0; c < CC; ++c) {
            const float* xc = xb + c * HWSZ;
            const float v = w00 * xc[i00] + w01 * xc[i01] +
                            w10 * xc[i10] + w11 * xc[i11];
#pragma unroll
            for (int j = 0; j < 16; ++j)
                acc[j] += v * wd[(size_t)((o0 + j) * CC + c) * 9 + kk];
        }
    }
#pragma unroll
    for (int j = 0; j < 16; ++j)
        out[((size_t)b * OO + o0 + j) * HOWO + p] = acc[j];
}

// ---------------------------------------------------------------------------
extern "C" void kernel_launch(void* const* d_in, const int* in_sizes, int n_in,
                              void* d_out, int out_size, void* d_ws, size_t ws_size,
                              hipStream_t stream)
{
    const float* x_off  = (const float*)d_in[0];
    const float* x_real = (const float*)d_in[1];
    const float* w_om   = (const float*)d_in[2];
    const float* b_om   = (const float*)d_in[3];
    const float* w_dcn  = (const float*)d_in[4];
    const float* b_dcn  = (const float*)d_in[5];

    float* out = (float*)d_out;
    const int outElems = BB * OO * HOWO;
    float* off_out = out + outElems;              // [B][18][HoWo]

    const size_t wtDcnFloats = 9 * 64 * 64;
    const size_t wtOmFloats  = 9 * 64 * 28;
    const size_t need = (wtDcnFloats + wtOmFloats) * sizeof(float);

    if (ws_size >= need) {
        float* wtDcn = (float*)d_ws;
        float* wtOm  = wtDcn + wtDcnFloats;
        hipLaunchKernelGGL(prep_transpose, dim3(144), dim3(256), 0, stream,
                           w_dcn, w_om, wtDcn, wtOm);
        hipLaunchKernelGGL(fused_dcn_kernel, dim3(1024), dim3(256), 0, stream,
                           x_off, x_real, wtOm, b_om, wtDcn, b_dcn,
                           out, off_out);
    } else {
        hipLaunchKernelGGL(conv_om_slow, dim3(128, 2), dim3(256), 0, stream,
                           x_off, w_om, b_om, off_out);
        hipLaunchKernelGGL(dcn_slow, dim3(128, 4), dim3(256), 0, stream,
                           x_real, off_out, w_dcn, b_dcn, out,
                           x_off, w_om, b_om);
    }
}

// Round 4
// 236.390 us; speedup vs baseline: 2.7517x; 2.7517x over previous
//
#include <hip/hip_runtime.h>
#include <math.h>

constexpr int BB   = 2;
constexpr int CC   = 64;
constexpr int HH   = 128;
constexpr int WW   = 128;
constexpr int OO   = 64;
constexpr int HWSZ = HH * WW;    // 16384
constexpr int HOWO = 16384;
constexpr int OMC  = 27;

// ---------------------------------------------------------------------------
// Prep: wt_om [9][64][28] (27 padded to 28 with zeros), wt_dcn [9][64][64]
// ---------------------------------------------------------------------------
__global__ __launch_bounds__(256) void prep_transpose(
    const float* __restrict__ w_dcn, const float* __restrict__ w_om,
    float* __restrict__ wt_dcn, float* __restrict__ wt_om)
{
    int idx = blockIdx.x * 256 + threadIdx.x;
    if (idx < 9 * 64 * 64) {
        int o  = idx & 63;
        int c  = (idx >> 6) & 63;
        int kk = idx >> 12;
        wt_dcn[idx] = w_dcn[(o * CC + c) * 9 + kk];
    }
    if (idx < 9 * 64 * 28) {
        int o    = idx % 28;
        int rest = idx / 28;
        int c    = rest & 63;
        int kk   = rest >> 6;
        wt_om[idx] = (o < OMC) ? w_om[(o * CC + c) * 9 + kk] : 0.f;
    }
}

__device__ __forceinline__ void bilinear_params(
    float oy, float ox, float m, int ho, int wo, int ky, int kx,
    float& w00, float& w01, float& w10, float& w11,
    int& i00, int& i01, int& i10, int& i11)
{
    const float yf = (float)(ho + ky - 1) + oy;
    const float xf = (float)(wo + kx - 1) + ox;
    const float y0 = floorf(yf), x0 = floorf(xf);
    const float ly = yf - y0, lx = xf - x0;
    const float hy = 1.f - ly, hx = 1.f - lx;
    const int iy0 = (int)y0, ix0 = (int)x0;
    const int iy1 = iy0 + 1, ix1 = ix0 + 1;
    const bool vy0 = (unsigned)iy0 < (unsigned)HH;
    const bool vy1 = (unsigned)iy1 < (unsigned)HH;
    const bool vx0 = (unsigned)ix0 < (unsigned)WW;
    const bool vx1 = (unsigned)ix1 < (unsigned)WW;
    w00 = (vy0 && vx0) ? hy * hx * m : 0.f;
    w01 = (vy0 && vx1) ? hy * lx * m : 0.f;
    w10 = (vy1 && vx0) ? ly * hx * m : 0.f;
    w11 = (vy1 && vx1) ? ly * lx * m : 0.f;
    const int cy0 = min(max(iy0, 0), HH - 1), cy1 = min(max(iy1, 0), HH - 1);
    const int cx0 = min(max(ix0, 0), WW - 1), cx1 = min(max(ix1, 0), WW - 1);
    i00 = cy0 * WW + cx0; i01 = cy0 * WW + cx1;
    i10 = cy1 * WW + cx0; i11 = cy1 * WW + cx1;
}

// ---------------------------------------------------------------------------
// Kernel A: 3x3 pad1 conv -> 27 ch. Thread = pixel x 8-oc-group.
// grid (128, 4). Only arrays: acc[8], t[9] (all compile-time indexed).
// Weights are block-uniform -> scalar loads, FMA with SGPR operand.
// ---------------------------------------------------------------------------
__global__ __launch_bounds__(256) void conv_om2(
    const float* __restrict__ x,       // input_offset
    const float* __restrict__ wtom,    // [9][64][28]
    const float* __restrict__ bom,     // [27]
    float* __restrict__ off_out,       // [B][18][HoWo]
    float* __restrict__ mask_out)      // [B][9][HoWo]
{
    const int pg  = blockIdx.x * 256 + threadIdx.x;   // 0..32767
    const int b   = pg >> 14;
    const int p   = pg & 16383;
    const int ho  = p >> 7, wo = p & 127;
    const int oc0 = blockIdx.y << 3;                  // 0,8,16,24

    float acc[8];
#pragma unroll
    for (int j = 0; j < 8; ++j) acc[j] = 0.f;

    const float* xb = x + (size_t)b * CC * HWSZ;
    for (int c = 0; c < CC; ++c) {
        const float* xc = xb + c * HWSZ;
        float t[9];
#pragma unroll
        for (int kh = 0; kh < 3; ++kh) {
            const int ih = ho + kh - 1;
            const bool rv = (unsigned)ih < (unsigned)HH;
#pragma unroll
            for (int kw = 0; kw < 3; ++kw) {
                const int iw = wo + kw - 1;
                t[kh * 3 + kw] =
                    (rv && (unsigned)iw < (unsigned)WW) ? xc[ih * WW + iw] : 0.f;
            }
        }
#pragma unroll
        for (int kk = 0; kk < 9; ++kk) {
            const float tv = t[kk];
            const float4* wr =
                (const float4*)(wtom + ((kk << 6) + c) * 28 + oc0);
            const float4 w0 = wr[0];
            const float4 w1 = wr[1];
            acc[0] += tv * w0.x;
            acc[1] += tv * w0.y;
            acc[2] += tv * w0.z;
            acc[3] += tv * w0.w;
            acc[4] += tv * w1.x;
            acc[5] += tv * w1.y;
            acc[6] += tv * w1.z;
            acc[7] += tv * w1.w;
        }
    }

#pragma unroll
    for (int j = 0; j < 8; ++j) {
        const int oc = oc0 + j;
        if (oc < 18) {
            off_out[(b * 18 + oc) * HOWO + p] = acc[j] + bom[oc];
        } else if (oc < OMC) {
            mask_out[(b * 9 + (oc - 18)) * HOWO + p] =
                1.f / (1.f + expf(-(acc[j] + bom[oc])));
        }
    }
}

// ---------------------------------------------------------------------------
// Kernel B: deformable conv. Block = 32 pixels x 8 groups, grid 1024.
// Per kk: gather v once per (c,pix) -> LDS vtile; barrier; GEMM acc[8]
// over all 64 c (v broadcast from LDS, 2 float4 L1-resident weight loads).
// Only per-thread array: acc[8]. No cross-phase register staging.
// ---------------------------------------------------------------------------
__global__ __launch_bounds__(256) void dcn2(
    const float* __restrict__ xr,     // input_real
    const float* __restrict__ off,    // [B][18][HoWo]
    const float* __restrict__ mask,   // [B][9][HoWo]
    const float* __restrict__ wtd,    // [9][64][64]
    const float* __restrict__ bd,     // [64]
    float* __restrict__ out)          // [B][64][HoWo]
{
    __shared__ float offm[32][29];    // [pix][0..17]=off, [18..26]=mask
    __shared__ float vtile[64 * 33];  // [c][pix], stride 33

    const int tid  = threadIdx.x;
    const int pixl = tid & 31;
    const int grp  = tid >> 5;                  // 0..7
    const int p0g  = blockIdx.x * 32;
    const int b    = p0g >> 14;
    const int p0   = p0g & 16383;
    const int p    = p0 + pixl;
    const int ho   = p >> 7, wo = p & 127;

    // stage the 27 per-pixel offset/mask values (coalesced)
    for (int it = tid; it < 32 * 27; it += 256) {
        const int pp = it & 31;
        const int o  = it >> 5;
        offm[pp][o] = (o < 18)
            ? off[(b * 18 + o) * HOWO + p0 + pp]
            : mask[(b * 9 + (o - 18)) * HOWO + p0 + pp];
    }
    __syncthreads();

    float acc[8];
#pragma unroll
    for (int j = 0; j < 8; ++j) acc[j] = 0.f;

    const float* xrb = xr + (size_t)b * CC * HWSZ;

    for (int kk = 0; kk < 9; ++kk) {
        // ---- gather: 8 bilinear samples for this thread's channels
        {
            const int ky = kk / 3, kx = kk - ky * 3;
            float w00, w01, w10, w11; int i00, i01, i10, i11;
            bilinear_params(offm[pixl][2 * kk], offm[pixl][2 * kk + 1],
                            offm[pixl][18 + kk], ho, wo, ky, kx,
                            w00, w01, w10, w11, i00, i01, i10, i11);
            const float* xg = xrb + (grp << 3) * HWSZ;
#pragma unroll
            for (int i = 0; i < 8; ++i) {
                const float* xc = xg + i * HWSZ;
                const float v = w00 * xc[i00] + w01 * xc[i01] +
                                w10 * xc[i10] + w11 * xc[i11];
                vtile[((grp << 3) + i) * 33 + pixl] = v;
            }
        }
        __syncthreads();

        // ---- GEMM: acc[0..7] over all 64 channels
        const float* wk = wtd + (kk << 12) + (grp << 3);
#pragma unroll 8
        for (int c = 0; c < 64; ++c) {
            const float v = vtile[c * 33 + pixl];
            const float4* wr = (const float4*)(wk + (c << 6));
            const float4 w0 = wr[0];
            const float4 w1 = wr[1];
            acc[0] += v * w0.x;
            acc[1] += v * w0.y;
            acc[2] += v * w0.z;
            acc[3] += v * w0.w;
            acc[4] += v * w1.x;
            acc[5] += v * w1.y;
            acc[6] += v * w1.z;
            acc[7] += v * w1.w;
        }
        __syncthreads();
    }

#pragma unroll
    for (int q = 0; q < 8; ++q) {
        const int oc = (grp << 3) + q;
        out[((size_t)(b * OO + oc)) * HOWO + p0 + pixl] = acc[q] + bd[oc];
    }
}

// ---------------------------------------------------------------------------
// Slow fallback (round-0, verified): used only if ws_size is too small.
// ---------------------------------------------------------------------------
__global__ __launch_bounds__(256) void conv_om_slow(
    const float* __restrict__ x, const float* __restrict__ w,
    const float* __restrict__ bias, float* __restrict__ off_out)
{
    const int xid = blockIdx.x;
    const int b   = xid >> 6;
    const int p   = ((xid & 63) << 8) + threadIdx.x;
    const int ho  = p >> 7, wo = p & 127;
    const int oc0 = blockIdx.y << 4;

    float acc[16];
#pragma unroll
    for (int j = 0; j < 16; ++j) {
        const int oc = oc0 + j;
        acc[j] = (oc < OMC) ? bias[oc] : 0.f;
    }
    const float* xb = x + (size_t)b * CC * HWSZ;
    for (int c = 0; c < CC; ++c) {
        const float* xc = xb + c * HWSZ;
        float t[9];
#pragma unroll
        for (int kh = 0; kh < 3; ++kh) {
            const int ih = ho + kh - 1;
            const bool rv = (unsigned)ih < (unsigned)HH;
#pragma unroll
            for (int kw = 0; kw < 3; ++kw) {
                const int iw = wo + kw - 1;
                t[kh * 3 + kw] =
                    (rv && (unsigned)iw < (unsigned)WW) ? xc[ih * WW + iw] : 0.f;
            }
        }
#pragma unroll
        for (int j = 0; j < 16; ++j) {
            const int oc = oc0 + j;
            if (oc < OMC) {
                const float* wj = w + (size_t)(oc * CC + c) * 9;
                float s = 0.f;
#pragma unroll
                for (int kk = 0; kk < 9; ++kk) s += t[kk] * wj[kk];
                acc[j] += s;
            }
        }
    }
#pragma unroll
    for (int j = 0; j < 16; ++j) {
        const int oc = oc0 + j;
        if (oc < 18) off_out[(b * 18 + oc) * HOWO + p] = acc[j];
    }
}

__global__ __launch_bounds__(256) void dcn_slow(
    const float* __restrict__ xr, const float* __restrict__ off,
    const float* __restrict__ wd, const float* __restrict__ bd,
    float* __restrict__ out, const float* __restrict__ xo,
    const float* __restrict__ wom, const float* __restrict__ bom)
{
    const int xid = blockIdx.x;
    const int b   = xid >> 6;
    const int p   = ((xid & 63) << 8) + threadIdx.x;
    const int ho  = p >> 7, wo = p & 127;
    const int o0  = blockIdx.y << 4;

    float acc[16];
#pragma unroll
    for (int j = 0; j < 16; ++j) acc[j] = bd[o0 + j];
    const float* xb = xr + (size_t)b * CC * HWSZ;

    for (int kk = 0; kk < 9; ++kk) {
        const float oy = off[(b * 18 + 2 * kk) * HOWO + p];
        const float ox = off[(b * 18 + 2 * kk + 1) * HOWO + p];
        float a = bom[18 + kk];
        const float* xob = xo + (size_t)b * CC * HWSZ;
        for (int c = 0; c < CC; ++c) {
            const float* xc2 = xob + c * HWSZ;
            const float* wj  = wom + (size_t)((18 + kk) * CC + c) * 9;
#pragma unroll
            for (int kh = 0; kh < 3; ++kh) {
                const int ih = ho + kh - 1;
                if ((unsigned)ih < (unsigned)HH) {
#pragma unroll
                    for (int kw = 0; kw < 3; ++kw) {
                        const int iw = wo + kw - 1;
                        if ((unsigned)iw < (unsigned)WW)
                            a += xc2[ih * WW + iw] * wj[kh * 3 + kw];
                    }
                }
            }
        }
        const float m = 1.f / (1.f + expf(-a));

        const int ky = kk / 3, kx = kk - ky * 3;
        float w00, w01, w10, w11; int i00, i01, i10, i11;
        bilinear_params(oy, ox, m, ho, wo, ky, kx,
                        w00, w01, w10, w11, i00, i01, i10, i11);

#pragma unroll 4
        for (int c = 0; c < CC; ++c) {
            const float* xc = xb + c * HWSZ;
            const float v = w00 * xc[i00] + w01 * xc[i01] +
                            w10 * xc[i10] + w11 * xc[i11];
#pragma unroll
            for (int j = 0; j < 16; ++j)
                acc[j] += v * wd[(size_t)((o0 + j) * CC + c) * 9 + kk];
        }
    }
#pragma unroll
    for (int j = 0; j < 16; ++j)
        out[((size_t)b * OO + o0 + j) * HOWO + p] = acc[j];
}

// ---------------------------------------------------------------------------
extern "C" void kernel_launch(void* const* d_in, const int* in_sizes, int n_in,
                              void* d_out, int out_size, void* d_ws, size_t ws_size,
                              hipStream_t stream)
{
    const float* x_off  = (const float*)d_in[0];
    const float* x_real = (const float*)d_in[1];
    const float* w_om   = (const float*)d_in[2];
    const float* b_om   = (const float*)d_in[3];
    const float* w_dcn  = (const float*)d_in[4];
    const float* b_dcn  = (const float*)d_in[5];

    float* out = (float*)d_out;
    const int outElems = BB * OO * HOWO;
    float* off_out = out + outElems;                  // [B][18][HoWo]

    const size_t wtDcnFloats = 9 * 64 * 64;           // 36864
    const size_t wtOmFloats  = 9 * 64 * 28;           // 16128
    const size_t maskFloats  = (size_t)BB * 9 * HOWO; // 294912
    const size_t need = (wtDcnFloats + wtOmFloats + maskFloats) * sizeof(float);

    if (ws_size >= need) {
        float* wtDcn   = (float*)d_ws;
        float* wtOm    = wtDcn + wtDcnFloats;
        float* maskBuf = wtOm + wtOmFloats;
        hipLaunchKernelGGL(prep_transpose, dim3(144), dim3(256), 0, stream,
                           w_dcn, w_om, wtDcn, wtOm);
        hipLaunchKernelGGL(conv_om2, dim3(128, 4), dim3(256), 0, stream,
                           x_off, wtOm, b_om, off_out, maskBuf);
        hipLaunchKernelGGL(dcn2, dim3(1024), dim3(256), 0, stream,
                           x_real, off_out, maskBuf, wtDcn, b_dcn, out);
    } else {
        hipLaunchKernelGGL(conv_om_slow, dim3(128, 2), dim3(256), 0, stream,
                           x_off, w_om, b_om, off_out);
        hipLaunchKernelGGL(dcn_slow, dim3(128, 4), dim3(256), 0, stream,
                           x_real, off_out, w_dcn, b_dcn, out,
                           x_off, w_om, b_om);
    }
}

// Round 5
// 88.663 us; speedup vs baseline: 7.3364x; 2.6662x over previous
//
#include <hip/hip_runtime.h>
#include <math.h>

constexpr int BB   = 2;
constexpr int CC   = 64;
constexpr int HH   = 128;
constexpr int WW   = 128;
constexpr int OO   = 64;
constexpr int HWSZ = HH * WW;    // 16384
constexpr int HOWO = 16384;
constexpr int OMC  = 27;

typedef __attribute__((ext_vector_type(8))) short short8v;  // 8 bf16
typedef __attribute__((ext_vector_type(4))) float f32x4;

__device__ __forceinline__ unsigned short f2bf(float x) {
    unsigned int u = __builtin_bit_cast(unsigned int, x);
    u = (u + 0x7FFFu + ((u >> 16) & 1u)) >> 16;   // RTNE
    return (unsigned short)u;
}

// ---------------------------------------------------------------------------
// Prep: wt_om [9][64][28]; wt_dcn [9][64][64] (fallback); Whi/Wlo [64][576] bf16
// k index = kk*64 + c
// ---------------------------------------------------------------------------
__global__ __launch_bounds__(256) void prep_transpose(
    const float* __restrict__ w_dcn, const float* __restrict__ w_om,
    float* __restrict__ wt_dcn, float* __restrict__ wt_om,
    unsigned short* __restrict__ Whi, unsigned short* __restrict__ Wlo)
{
    int idx = blockIdx.x * 256 + threadIdx.x;
    if (idx < 9 * 64 * 64) {
        int o  = idx & 63;
        int c  = (idx >> 6) & 63;
        int kk = idx >> 12;
        wt_dcn[idx] = w_dcn[(o * CC + c) * 9 + kk];

        // Whi/Wlo: element (o2, k) with k = kk2*64 + c2
        int o2 = idx / 576;
        int k  = idx - o2 * 576;
        int kk2 = k >> 6;
        int c2  = k & 63;
        float w = w_dcn[(o2 * CC + c2) * 9 + kk2];
        unsigned short hi = f2bf(w);
        float hif = __builtin_bit_cast(float, (unsigned int)hi << 16);
        Whi[idx] = hi;
        Wlo[idx] = f2bf(w - hif);
    }
    if (idx < 9 * 64 * 28) {
        int o    = idx % 28;
        int rest = idx / 28;
        int c    = rest & 63;
        int kk   = rest >> 6;
        wt_om[idx] = (o < OMC) ? w_om[(o * CC + c) * 9 + kk] : 0.f;
    }
}

// ---------------------------------------------------------------------------
// Channels-last transpose: x[b][c][y][x] -> xt[((b*128+y)*128+x)*64 + c]
// grid = B*H blocks; LDS tile transpose, coalesced both sides.
// ---------------------------------------------------------------------------
__global__ __launch_bounds__(256) void xtpose(
    const float* __restrict__ xin, float* __restrict__ xt)
{
    __shared__ float t[64][129];
    const int tid = threadIdx.x;
    const int by  = blockIdx.x;          // b*128 + y
    const int b   = by >> 7, y = by & 127;

#pragma unroll
    for (int cc = 0; cc < 64; cc += 2) {
        const int c  = cc + (tid >> 7);
        const int xw = tid & 127;
        t[c][xw] = xin[((size_t)(b * 64 + c) * 128 + y) * 128 + xw];
    }
    __syncthreads();

#pragma unroll
    for (int r = 0; r < 8; ++r) {
        const int idx = r * 256 + tid;
        const int xw  = idx >> 4;
        const int cq  = (idx & 15) << 2;
        float4 vq = make_float4(t[cq][xw], t[cq + 1][xw],
                                t[cq + 2][xw], t[cq + 3][xw]);
        *(float4*)(xt + (((size_t)by * 128 + xw) << 6) + cq) = vq;
    }
}

__device__ __forceinline__ void bilinear_params(
    float oy, float ox, float m, int ho, int wo, int ky, int kx,
    float& w00, float& w01, float& w10, float& w11,
    int& i00, int& i01, int& i10, int& i11)
{
    const float yf = (float)(ho + ky - 1) + oy;
    const float xf = (float)(wo + kx - 1) + ox;
    const float y0 = floorf(yf), x0 = floorf(xf);
    const float ly = yf - y0, lx = xf - x0;
    const float hy = 1.f - ly, hx = 1.f - lx;
    const int iy0 = (int)y0, ix0 = (int)x0;
    const int iy1 = iy0 + 1, ix1 = ix0 + 1;
    const bool vy0 = (unsigned)iy0 < (unsigned)HH;
    const bool vy1 = (unsigned)iy1 < (unsigned)HH;
    const bool vx0 = (unsigned)ix0 < (unsigned)WW;
    const bool vx1 = (unsigned)ix1 < (unsigned)WW;
    w00 = (vy0 && vx0) ? hy * hx * m : 0.f;
    w01 = (vy0 && vx1) ? hy * lx * m : 0.f;
    w10 = (vy1 && vx0) ? ly * hx * m : 0.f;
    w11 = (vy1 && vx1) ? ly * lx * m : 0.f;
    const int cy0 = min(max(iy0, 0), HH - 1), cy1 = min(max(iy1, 0), HH - 1);
    const int cx0 = min(max(ix0, 0), WW - 1), cx1 = min(max(ix1, 0), WW - 1);
    i00 = cy0 * WW + cx0; i01 = cy0 * WW + cx1;
    i10 = cy1 * WW + cx0; i11 = cy1 * WW + cx1;
}

// ---------------------------------------------------------------------------
// Kernel A: 3x3 pad1 conv -> 27 ch (fp32, proven). Thread = pixel x 8-oc.
// ---------------------------------------------------------------------------
__global__ __launch_bounds__(256) void conv_om2(
    const float* __restrict__ x, const float* __restrict__ wtom,
    const float* __restrict__ bom, float* __restrict__ off_out,
    float* __restrict__ mask_out)
{
    const int pg  = blockIdx.x * 256 + threadIdx.x;
    const int b   = pg >> 14;
    const int p   = pg & 16383;
    const int ho  = p >> 7, wo = p & 127;
    const int oc0 = blockIdx.y << 3;

    float acc[8];
#pragma unroll
    for (int j = 0; j < 8; ++j) acc[j] = 0.f;

    const float* xb = x + (size_t)b * CC * HWSZ;
    for (int c = 0; c < CC; ++c) {
        const float* xc = xb + c * HWSZ;
        float t[9];
#pragma unroll
        for (int kh = 0; kh < 3; ++kh) {
            const int ih = ho + kh - 1;
            const bool rv = (unsigned)ih < (unsigned)HH;
#pragma unroll
            for (int kw = 0; kw < 3; ++kw) {
                const int iw = wo + kw - 1;
                t[kh * 3 + kw] =
                    (rv && (unsigned)iw < (unsigned)WW) ? xc[ih * WW + iw] : 0.f;
            }
        }
#pragma unroll
        for (int kk = 0; kk < 9; ++kk) {
            const float tv = t[kk];
            const float4* wr = (const float4*)(wtom + ((kk << 6) + c) * 28 + oc0);
            const float4 w0 = wr[0];
            const float4 w1 = wr[1];
            acc[0] += tv * w0.x; acc[1] += tv * w0.y;
            acc[2] += tv * w0.z; acc[3] += tv * w0.w;
            acc[4] += tv * w1.x; acc[5] += tv * w1.y;
            acc[6] += tv * w1.z; acc[7] += tv * w1.w;
        }
    }
#pragma unroll
    for (int j = 0; j < 8; ++j) {
        const int oc = oc0 + j;
        if (oc < 18) {
            off_out[(b * 18 + oc) * HOWO + p] = acc[j] + bom[oc];
        } else if (oc < OMC) {
            mask_out[(b * 9 + (oc - 18)) * HOWO + p] =
                1.f / (1.f + expf(-(acc[j] + bom[oc])));
        }
    }
}

// ---------------------------------------------------------------------------
// Kernel B (MFMA): block = 64 pixels, 256 threads (4 waves).
// Phase 1: gather V[pix][k=kk*64+c] in bf16 into LDS (XOR-swizzled rows),
//          tasks of 8 threads each fetch 64 channels coalesced from xt.
// Phase 2: GEMM D[oc][pix] = (Whi+Wlo)[oc][k] * V[k][pix] via
//          v_mfma_f32_16x16x32_bf16; wave w owns oc 16w..16w+15, all 64 pix.
// ---------------------------------------------------------------------------
__global__ __launch_bounds__(256, 2) void dcn_mfma(
    const float* __restrict__ xt,     // channels-last input_real
    const float* __restrict__ off,    // [B][18][HoWo]
    const float* __restrict__ mask,   // [B][9][HoWo]
    const unsigned short* __restrict__ Whi,  // [64][576] bf16
    const unsigned short* __restrict__ Wlo,  // [64][576] bf16
    const float* __restrict__ bd,     // [64]
    float* __restrict__ out)          // [B][64][HoWo]
{
    __shared__ unsigned short vlds[64 * 576];   // 72 KB, row = pix (1152 B)
    __shared__ float offm[64][28];              // 7 KB

    const int tid = threadIdx.x;
    const int p0  = blockIdx.x * 64;            // global pixel base
    const int b   = p0 >> 14;
    const int pl  = p0 & 16383;                 // local pixel base

    // ---- stage offsets/mask (coalesced)
    for (int it = tid; it < 64 * 27; it += 256) {
        const int pp = it & 63;
        const int o  = it >> 6;
        offm[pp][o] = (o < 18)
            ? off[(b * 18 + o) * HOWO + pl + pp]
            : mask[(b * 9 + (o - 18)) * HOWO + pl + pp];
    }
    __syncthreads();

    // ---- gather phase: 576 tasks (pix,kk), 8 threads/task, 18 rounds
    {
        const int s   = tid & 7;
        const int ch0 = s << 3;
        const int bofs = b << 14;
#pragma unroll 2
        for (int rnd = 0; rnd < 18; ++rnd) {
            const int task = rnd * 32 + (tid >> 3);
            const int pix  = task & 63;
            const int kk   = task >> 6;
            const int pg   = pl + pix;
            const int ho   = pg >> 7, wo = pg & 127;
            const int ky   = kk / 3, kx = kk - 3 * ky;

            float w00, w01, w10, w11; int i00, i01, i10, i11;
            bilinear_params(offm[pix][2 * kk], offm[pix][2 * kk + 1],
                            offm[pix][18 + kk], ho, wo, ky, kx,
                            w00, w01, w10, w11, i00, i01, i10, i11);

            const float* q00 = xt + ((size_t)(bofs + i00) << 6) + ch0;
            const float* q01 = xt + ((size_t)(bofs + i01) << 6) + ch0;
            const float* q10 = xt + ((size_t)(bofs + i10) << 6) + ch0;
            const float* q11 = xt + ((size_t)(bofs + i11) << 6) + ch0;
            const float4 a0 = *(const float4*)q00;
            const float4 a1 = *(const float4*)(q00 + 4);
            const float4 b0 = *(const float4*)q01;
            const float4 b1 = *(const float4*)(q01 + 4);
            const float4 c0 = *(const float4*)q10;
            const float4 c1 = *(const float4*)(q10 + 4);
            const float4 d0 = *(const float4*)q11;
            const float4 d1 = *(const float4*)(q11 + 4);

            short8v pk;
            pk[0] = (short)f2bf(w00 * a0.x + w01 * b0.x + w10 * c0.x + w11 * d0.x);
            pk[1] = (short)f2bf(w00 * a0.y + w01 * b0.y + w10 * c0.y + w11 * d0.y);
            pk[2] = (short)f2bf(w00 * a0.z + w01 * b0.z + w10 * c0.z + w11 * d0.z);
            pk[3] = (short)f2bf(w00 * a0.w + w01 * b0.w + w10 * c0.w + w11 * d0.w);
            pk[4] = (short)f2bf(w00 * a1.x + w01 * b1.x + w10 * c1.x + w11 * d1.x);
            pk[5] = (short)f2bf(w00 * a1.y + w01 * b1.y + w10 * c1.y + w11 * d1.y);
            pk[6] = (short)f2bf(w00 * a1.z + w01 * b1.z + w10 * c1.z + w11 * d1.z);
            pk[7] = (short)f2bf(w00 * a1.w + w01 * b1.w + w10 * c1.w + w11 * d1.w);

            // byte(k,pix) = pix*1152 + ((2k) ^ ((pix&7)<<4)), k = kk*64+ch0
            const int inrow = (((kk << 6) + ch0) << 1) ^ ((pix & 7) << 4);
            *(short8v*)((char*)vlds + pix * 1152 + inrow) = pk;
        }
    }
    __syncthreads();

    // ---- GEMM phase
    {
        const int lane = tid & 63;
        const int wid  = tid >> 6;        // 0..3
        const int l15  = lane & 15;
        const int l4   = lane >> 4;       // 0..3
        const int oc0  = wid << 4;

        const unsigned short* whiRow = Whi + (oc0 + l15) * 576 + (l4 << 3);
        const unsigned short* wloRow = Wlo + (oc0 + l15) * 576 + (l4 << 3);
        const int swz = (l15 & 7) << 4;
        const int kl  = l4 << 4;          // 16*l4 = byte offset of 8*l4 elems

        f32x4 ac0 = {0.f, 0.f, 0.f, 0.f};
        f32x4 ac1 = {0.f, 0.f, 0.f, 0.f};
        f32x4 ac2 = {0.f, 0.f, 0.f, 0.f};
        f32x4 ac3 = {0.f, 0.f, 0.f, 0.f};

#pragma unroll
        for (int ks = 0; ks < 18; ++ks) {
            const int k0 = ks * 32;
            const short8v ahi = *(const short8v*)(whiRow + k0);
            const short8v alo = *(const short8v*)(wloRow + k0);
            const int inrow = ((k0 << 1) + kl) ^ swz;
            const char* base = (const char*)vlds + inrow;
            const short8v b0 = *(const short8v*)(base + (l15 + 0)  * 1152);
            const short8v b1 = *(const short8v*)(base + (l15 + 16) * 1152);
            const short8v b2 = *(const short8v*)(base + (l15 + 32) * 1152);
            const short8v b3 = *(const short8v*)(base + (l15 + 48) * 1152);
            ac0 = __builtin_amdgcn_mfma_f32_16x16x32_bf16(ahi, b0, ac0, 0, 0, 0);
            ac0 = __builtin_amdgcn_mfma_f32_16x16x32_bf16(alo, b0, ac0, 0, 0, 0);
            ac1 = __builtin_amdgcn_mfma_f32_16x16x32_bf16(ahi, b1, ac1, 0, 0, 0);
            ac1 = __builtin_amdgcn_mfma_f32_16x16x32_bf16(alo, b1, ac1, 0, 0, 0);
            ac2 = __builtin_amdgcn_mfma_f32_16x16x32_bf16(ahi, b2, ac2, 0, 0, 0);
            ac2 = __builtin_amdgcn_mfma_f32_16x16x32_bf16(alo, b2, ac2, 0, 0, 0);
            ac3 = __builtin_amdgcn_mfma_f32_16x16x32_bf16(ahi, b3, ac3, 0, 0, 0);
            ac3 = __builtin_amdgcn_mfma_f32_16x16x32_bf16(alo, b3, ac3, 0, 0, 0);
        }

        // C/D: col = lane&15 (pix), row = (lane>>4)*4 + reg (oc)
#pragma unroll
        for (int r = 0; r < 4; ++r) {
            const int oc = oc0 + (l4 << 2) + r;
            const float bias = bd[oc];
            const size_t ob = ((size_t)(b * OO + oc)) * HOWO + pl + l15;
            out[ob + 0]  = ac0[r] + bias;
            out[ob + 16] = ac1[r] + bias;
            out[ob + 32] = ac2[r] + bias;
            out[ob + 48] = ac3[r] + bias;
        }
    }
}

// ---------------------------------------------------------------------------
// Mid fallback: round-4 dcn2 (proven, 194 us)
// ---------------------------------------------------------------------------
__global__ __launch_bounds__(256) void dcn2(
    const float* __restrict__ xr, const float* __restrict__ off,
    const float* __restrict__ mask, const float* __restrict__ wtd,
    const float* __restrict__ bd, float* __restrict__ out)
{
    __shared__ float offm[32][29];
    __shared__ float vtile[64 * 33];

    const int tid  = threadIdx.x;
    const int pixl = tid & 31;
    const int grp  = tid >> 5;
    const int p0g  = blockIdx.x * 32;
    const int b    = p0g >> 14;
    const int p0   = p0g & 16383;
    const int p    = p0 + pixl;
    const int ho   = p >> 7, wo = p & 127;

    for (int it = tid; it < 32 * 27; it += 256) {
        const int pp = it & 31;
        const int o  = it >> 5;
        offm[pp][o] = (o < 18)
            ? off[(b * 18 + o) * HOWO + p0 + pp]
            : mask[(b * 9 + (o - 18)) * HOWO + p0 + pp];
    }
    __syncthreads();

    float acc[8];
#pragma unroll
    for (int j = 0; j < 8; ++j) acc[j] = 0.f;

    const float* xrb = xr + (size_t)b * CC * HWSZ;

    for (int kk = 0; kk < 9; ++kk) {
        {
            const int ky = kk / 3, kx = kk - ky * 3;
            float w00, w01, w10, w11; int i00, i01, i10, i11;
            bilinear_params(offm[pixl][2 * kk], offm[pixl][2 * kk + 1],
                            offm[pixl][18 + kk], ho, wo, ky, kx,
                            w00, w01, w10, w11, i00, i01, i10, i11);
            const float* xg = xrb + (grp << 3) * HWSZ;
#pragma unroll
            for (int i = 0; i < 8; ++i) {
                const float* xc = xg + i * HWSZ;
                const float v = w00 * xc[i00] + w01 * xc[i01] +
                                w10 * xc[i10] + w11 * xc[i11];
                vtile[((grp << 3) + i) * 33 + pixl] = v;
            }
        }
        __syncthreads();

        const float* wk = wtd + (kk << 12) + (grp << 3);
#pragma unroll 8
        for (int c = 0; c < 64; ++c) {
            const float v = vtile[c * 33 + pixl];
            const float4* wr = (const float4*)(wk + (c << 6));
            const float4 w0 = wr[0];
            const float4 w1 = wr[1];
            acc[0] += v * w0.x; acc[1] += v * w0.y;
            acc[2] += v * w0.z; acc[3] += v * w0.w;
            acc[4] += v * w1.x; acc[5] += v * w1.y;
            acc[6] += v * w1.z; acc[7] += v * w1.w;
        }
        __syncthreads();
    }

#pragma unroll
    for (int q = 0; q < 8; ++q) {
        const int oc = (grp << 3) + q;
        out[((size_t)(b * OO + oc)) * HOWO + p0 + pixl] = acc[q] + bd[oc];
    }
}

// ---------------------------------------------------------------------------
// Slow fallback (round-0, verified)
// ---------------------------------------------------------------------------
__global__ __launch_bounds__(256) void conv_om_slow(
    const float* __restrict__ x, const float* __restrict__ w,
    const float* __restrict__ bias, float* __restrict__ off_out)
{
    const int xid = blockIdx.x;
    const int b   = xid >> 6;
    const int p   = ((xid & 63) << 8) + threadIdx.x;
    const int ho  = p >> 7, wo = p & 127;
    const int oc0 = blockIdx.y << 4;

    float acc[16];
#pragma unroll
    for (int j = 0; j < 16; ++j) {
        const int oc = oc0 + j;
        acc[j] = (oc < OMC) ? bias[oc] : 0.f;
    }
    const float* xb = x + (size_t)b * CC * HWSZ;
    for (int c = 0; c < CC; ++c) {
        const float* xc = xb + c * HWSZ;
        float t[9];
#pragma unroll
        for (int kh = 0; kh < 3; ++kh) {
            const int ih = ho + kh - 1;
            const bool rv = (unsigned)ih < (unsigned)HH;
#pragma unroll
            for (int kw = 0; kw < 3; ++kw) {
                const int iw = wo + kw - 1;
                t[kh * 3 + kw] =
                    (rv && (unsigned)iw < (unsigned)WW) ? xc[ih * WW + iw] : 0.f;
            }
        }
#pragma unroll
        for (int j = 0; j < 16; ++j) {
            const int oc = oc0 + j;
            if (oc < OMC) {
                const float* wj = w + (size_t)(oc * CC + c) * 9;
                float s = 0.f;
#pragma unroll
                for (int kk = 0; kk < 9; ++kk) s += t[kk] * wj[kk];
                acc[j] += s;
            }
        }
    }
#pragma unroll
    for (int j = 0; j < 16; ++j) {
        const int oc = oc0 + j;
        if (oc < 18) off_out[(b * 18 + oc) * HOWO + p] = acc[j];
    }
}

__global__ __launch_bounds__(256) void dcn_slow(
    const float* __restrict__ xr, const float* __restrict__ off,
    const float* __restrict__ wd, const float* __restrict__ bd,
    float* __restrict__ out, const float* __restrict__ xo,
    const float* __restrict__ wom, const float* __restrict__ bom)
{
    const int xid = blockIdx.x;
    const int b   = xid >> 6;
    const int p   = ((xid & 63) << 8) + threadIdx.x;
    const int ho  = p >> 7, wo = p & 127;
    const int o0  = blockIdx.y << 4;

    float acc[16];
#pragma unroll
    for (int j = 0; j < 16; ++j) acc[j] = bd[o0 + j];
    const float* xb = xr + (size_t)b * CC * HWSZ;

    for (int kk = 0; kk < 9; ++kk) {
        const float oy = off[(b * 18 + 2 * kk) * HOWO + p];
        const float ox = off[(b * 18 + 2 * kk + 1) * HOWO + p];
        float a = bom[18 + kk];
        const float* xob = xo + (size_t)b * CC * HWSZ;
        for (int c = 0; c < CC; ++c) {
            const float* xc2 = xob + c * HWSZ;
            const float* wj  = wom + (size_t)((18 + kk) * CC + c) * 9;
#pragma unroll
            for (int kh = 0; kh < 3; ++kh) {
                const int ih = ho + kh - 1;
                if ((unsigned)ih < (unsigned)HH) {
#pragma unroll
                    for (int kw = 0; kw < 3; ++kw) {
                        const int iw = wo + kw - 1;
                        if ((unsigned)iw < (unsigned)WW)
                            a += xc2[ih * WW + iw] * wj[kh * 3 + kw];
                    }
                }
            }
        }
        const float m = 1.f / (1.f + expf(-a));
        const int ky = kk / 3, kx = kk - ky * 3;
        float w00, w01, w10, w11; int i00, i01, i10, i11;
        bilinear_params(oy, ox, m, ho, wo, ky, kx,
                        w00, w01, w10, w11, i00, i01, i10, i11);
#pragma unroll 4
        for (int c = 0; c < CC; ++c) {
            const float* xc = xb + c * HWSZ;
            const float v = w00 * xc[i00] + w01 * xc[i01] +
                            w10 * xc[i10] + w11 * xc[i11];
#pragma unroll
            for (int j = 0; j < 16; ++j)
                acc[j] += v * wd[(size_t)((o0 + j) * CC + c) * 9 + kk];
        }
    }
#pragma unroll
    for (int j = 0; j < 16; ++j)
        out[((size_t)b * OO + o0 + j) * HOWO + p] = acc[j];
}

// ---------------------------------------------------------------------------
extern "C" void kernel_launch(void* const* d_in, const int* in_sizes, int n_in,
                              void* d_out, int out_size, void* d_ws, size_t ws_size,
                              hipStream_t stream)
{
    const float* x_off  = (const float*)d_in[0];
    const float* x_real = (const float*)d_in[1];
    const float* w_om   = (const float*)d_in[2];
    const float* b_om   = (const float*)d_in[3];
    const float* w_dcn  = (const float*)d_in[4];
    const float* b_dcn  = (const float*)d_in[5];

    float* out = (float*)d_out;
    const int outElems = BB * OO * HOWO;
    float* off_out = out + outElems;                  // [B][18][HoWo]

    const size_t wtDcnF = 9 * 64 * 64;                // 36864
    const size_t wtOmF  = 9 * 64 * 28;                // 16128
    const size_t maskF  = (size_t)BB * 9 * HOWO;      // 294912
    const size_t xtF    = (size_t)BB * HWSZ * CC;     // 2097152
    const size_t wSplitB = 2ull * 64 * 576 * sizeof(unsigned short);   // 147456 B

    float* wtDcn   = (float*)d_ws;
    float* wtOm    = wtDcn + wtDcnF;
    float* maskBuf = wtOm + wtOmF;

    const size_t need_mid  = (wtDcnF + wtOmF + maskF) * sizeof(float);
    const size_t need_full = need_mid + xtF * sizeof(float) + wSplitB;

    if (ws_size >= need_full) {
        float* xt = maskBuf + maskF;
        unsigned short* Whi = (unsigned short*)(xt + xtF);
        unsigned short* Wlo = Whi + 64 * 576;

        hipLaunchKernelGGL(prep_transpose, dim3(144), dim3(256), 0, stream,
                           w_dcn, w_om, wtDcn, wtOm, Whi, Wlo);
        hipLaunchKernelGGL(xtpose, dim3(BB * HH), dim3(256), 0, stream,
                           x_real, xt);
        hipLaunchKernelGGL(conv_om2, dim3(128, 4), dim3(256), 0, stream,
                           x_off, wtOm, b_om, off_out, maskBuf);
        hipLaunchKernelGGL(dcn_mfma, dim3(512), dim3(256), 0, stream,
                           xt, off_out, maskBuf, Whi, Wlo, b_dcn, out);
    } else if (ws_size >= need_mid) {
        hipLaunchKernelGGL(prep_transpose, dim3(144), dim3(256), 0, stream,
                           w_dcn, w_om, wtDcn, wtOm,
                           (unsigned short*)wtDcn, (unsigned short*)wtDcn);
        hipLaunchKernelGGL(conv_om2, dim3(128, 4), dim3(256), 0, stream,
                           x_off, wtOm, b_om, off_out, maskBuf);
        hipLaunchKernelGGL(dcn2, dim3(1024), dim3(256), 0, stream,
                           x_real, off_out, maskBuf, wtDcn, b_dcn, out);
    } else {
        hipLaunchKernelGGL(conv_om_slow, dim3(128, 2), dim3(256), 0, stream,
                           x_off, w_om, b_om, off_out);
        hipLaunchKernelGGL(dcn_slow, dim3(128, 4), dim3(256), 0, stream,
                           x_real, off_out, w_dcn, b_dcn, out,
                           x_off, w_om, b_om);
    }
}

// Round 6
// 62.617 us; speedup vs baseline: 10.3879x; 1.4159x over previous
//
#include <hip/hip_runtime.h>
#include <math.h>

constexpr int BB   = 2;
constexpr int CC   = 64;
constexpr int HH   = 128;
constexpr int WW   = 128;
constexpr int OO   = 64;
constexpr int HWSZ = HH * WW;    // 16384
constexpr int HOWO = 16384;
constexpr int OMC  = 27;

typedef __attribute__((ext_vector_type(8))) short short8v;  // 8 bf16
typedef __attribute__((ext_vector_type(4))) float f32x4;
typedef unsigned short ushortT;

__device__ __forceinline__ ushortT f2bf(float x) {
    unsigned int u = __builtin_bit_cast(unsigned int, x);
    u = (u + 0x7FFFu + ((u >> 16) & 1u)) >> 16;   // RTNE
    return (ushortT)u;
}
__device__ __forceinline__ float bf2f(ushortT u) {
    return __builtin_bit_cast(float, (unsigned int)u << 16);
}

// ---------------------------------------------------------------------------
// prep2 (full tier): Whi/Wlo [64][576] bf16 (k = kk*64+c), Womhi/Womlo
// [32][576] bf16 (ocs 27..31 zero-padded).
// ---------------------------------------------------------------------------
__global__ __launch_bounds__(256) void prep2(
    const float* __restrict__ w_dcn, const float* __restrict__ w_om,
    ushortT* __restrict__ Whi, ushortT* __restrict__ Wlo,
    ushortT* __restrict__ Womhi, ushortT* __restrict__ Womlo)
{
    int idx = blockIdx.x * 256 + threadIdx.x;
    if (idx < 64 * 576) {
        int o  = idx / 576;
        int k  = idx - o * 576;
        int kk = k >> 6;
        int c  = k & 63;
        float w = w_dcn[(o * CC + c) * 9 + kk];
        ushortT hi = f2bf(w);
        Whi[idx] = hi;
        Wlo[idx] = f2bf(w - bf2f(hi));
    }
    if (idx < 32 * 576) {
        int o  = idx / 576;
        int k  = idx - o * 576;
        int kk = k >> 6;
        int c  = k & 63;
        float w = (o < OMC) ? w_om[(o * CC + c) * 9 + kk] : 0.f;
        ushortT hi = f2bf(w);
        Womhi[idx] = hi;
        Womlo[idx] = f2bf(w - bf2f(hi));
    }
}

// ---------------------------------------------------------------------------
// xtpose2: NCHW fp32 -> channels-last bf16 [b*16384 + y*128 + x][64c].
// grid (BB*HH, 2): y-block picks the row, blockIdx.y picks the input.
// ---------------------------------------------------------------------------
__global__ __launch_bounds__(256) void xtpose2(
    const float* __restrict__ xr, const float* __restrict__ xo,
    ushortT* __restrict__ xtr, ushortT* __restrict__ xto)
{
    __shared__ float t[64][129];
    const int tid = threadIdx.x;
    const int by  = blockIdx.x;          // b*128 + y
    const int b   = by >> 7, y = by & 127;
    const float* src = blockIdx.y ? xo : xr;
    ushortT*    dst  = blockIdx.y ? xto : xtr;

#pragma unroll
    for (int cc = 0; cc < 64; cc += 2) {
        const int c  = cc + (tid >> 7);
        const int xw = tid & 127;
        t[c][xw] = src[((size_t)(b * 64 + c) * 128 + y) * 128 + xw];
    }
    __syncthreads();

#pragma unroll
    for (int r = 0; r < 8; ++r) {
        const int idx = r * 256 + tid;
        const int xw  = idx >> 4;
        const int cq  = (idx & 15) << 2;
        ushort4 pk = make_ushort4(f2bf(t[cq][xw]), f2bf(t[cq + 1][xw]),
                                  f2bf(t[cq + 2][xw]), f2bf(t[cq + 3][xw]));
        *(ushort4*)(dst + (((size_t)by * 128 + xw) << 6) + cq) = pk;
    }
}

__device__ __forceinline__ void bilinear_params(
    float oy, float ox, float m, int ho, int wo, int ky, int kx,
    float& w00, float& w01, float& w10, float& w11,
    int& i00, int& i01, int& i10, int& i11)
{
    const float yf = (float)(ho + ky - 1) + oy;
    const float xf = (float)(wo + kx - 1) + ox;
    const float y0 = floorf(yf), x0 = floorf(xf);
    const float ly = yf - y0, lx = xf - x0;
    const float hy = 1.f - ly, hx = 1.f - lx;
    const int iy0 = (int)y0, ix0 = (int)x0;
    const int iy1 = iy0 + 1, ix1 = ix0 + 1;
    const bool vy0 = (unsigned)iy0 < (unsigned)HH;
    const bool vy1 = (unsigned)iy1 < (unsigned)HH;
    const bool vx0 = (unsigned)ix0 < (unsigned)WW;
    const bool vx1 = (unsigned)ix1 < (unsigned)WW;
    w00 = (vy0 && vx0) ? hy * hx * m : 0.f;
    w01 = (vy0 && vx1) ? hy * lx * m : 0.f;
    w10 = (vy1 && vx0) ? ly * hx * m : 0.f;
    w11 = (vy1 && vx1) ? ly * lx * m : 0.f;
    const int cy0 = min(max(iy0, 0), HH - 1), cy1 = min(max(iy1, 0), HH - 1);
    const int cx0 = min(max(ix0, 0), WW - 1), cx1 = min(max(ix1, 0), WW - 1);
    i00 = cy0 * WW + cx0; i01 = cy0 * WW + cx1;
    i10 = cy1 * WW + cx0; i11 = cy1 * WW + cx1;
}

// ---------------------------------------------------------------------------
// conv_om_mfma: out_om[32][N] = Wom[32][576] x im2col[576][N] via MFMA.
// Block = 64 pixels, wave = 16 pixels x all 32 ocs. Per k-step: kk = ks>>1
// (wave-uniform), one 16B bf16 B-load per lane (clamped addr + select-zero
// for padding), 4 MFMAs (2 oc-groups x hi/lo). Mapping mirrors dcn_mfma.
// ---------------------------------------------------------------------------
__global__ __launch_bounds__(256) void conv_om_mfma(
    const ushortT* __restrict__ xto,    // bf16 channels-last input_offset
    const ushortT* __restrict__ Womhi,  // [32][576]
    const ushortT* __restrict__ Womlo,
    const float* __restrict__ bom,      // [27]
    float* __restrict__ off_out,        // [B][18][HoWo]
    float* __restrict__ mask_out)       // [B][9][HoWo]
{
    const int tid  = threadIdx.x;
    const int lane = tid & 63;
    const int wid  = tid >> 6;
    const int l15  = lane & 15;
    const int l4   = lane >> 4;
    const int p0   = blockIdx.x * 64;
    const int b    = p0 >> 14;
    const int pix  = (p0 & 16383) + (wid << 4) + l15;
    const int ho   = pix >> 7, wo = pix & 127;

    f32x4 acc0 = {0.f, 0.f, 0.f, 0.f};
    f32x4 acc1 = {0.f, 0.f, 0.f, 0.f};

    const ushortT* wh = Womhi + l15 * 576 + (l4 << 3);
    const ushortT* wl = Womlo + l15 * 576 + (l4 << 3);
    const size_t bbase = (size_t)(b << 14);
    const short8v zero8 = {0, 0, 0, 0, 0, 0, 0, 0};

#pragma unroll
    for (int ks = 0; ks < 18; ++ks) {
        const int kk = ks >> 1;
        const int ky = kk / 3, kx = kk - 3 * ky;
        const int iy = ho + ky - 1, ix = wo + kx - 1;
        const bool valid = ((unsigned)iy < 128u) && ((unsigned)ix < 128u);
        const int cy = min(max(iy, 0), 127), cx = min(max(ix, 0), 127);
        const int c0 = ((ks & 1) << 5) + (l4 << 3);
        const short8v braw =
            *(const short8v*)(xto + ((bbase + cy * 128 + cx) << 6) + c0);
        const short8v bf = valid ? braw : zero8;

        const int k0 = ks << 5;
        const short8v ah0 = *(const short8v*)(wh + k0);
        const short8v al0 = *(const short8v*)(wl + k0);
        const short8v ah1 = *(const short8v*)(wh + 16 * 576 + k0);
        const short8v al1 = *(const short8v*)(wl + 16 * 576 + k0);
        acc0 = __builtin_amdgcn_mfma_f32_16x16x32_bf16(ah0, bf, acc0, 0, 0, 0);
        acc0 = __builtin_amdgcn_mfma_f32_16x16x32_bf16(al0, bf, acc0, 0, 0, 0);
        acc1 = __builtin_amdgcn_mfma_f32_16x16x32_bf16(ah1, bf, acc1, 0, 0, 0);
        acc1 = __builtin_amdgcn_mfma_f32_16x16x32_bf16(al1, bf, acc1, 0, 0, 0);
    }

    // C/D: col = lane&15 (pix), row = (lane>>4)*4 + r (oc)
#pragma unroll
    for (int r = 0; r < 4; ++r) {
        const int oca = (l4 << 2) + r;            // 0..15: always offset
        off_out[(b * 18 + oca) * HOWO + pix] = acc0[r] + bom[oca];
        const int ocb = 16 + (l4 << 2) + r;       // 16..31
        if (ocb < 18) {
            off_out[(b * 18 + ocb) * HOWO + pix] = acc1[r] + bom[ocb];
        } else if (ocb < OMC) {
            mask_out[(b * 9 + (ocb - 18)) * HOWO + pix] =
                1.f / (1.f + expf(-(acc1[r] + bom[ocb])));
        }
    }
}

// ---------------------------------------------------------------------------
// dcn_mfma (verified in round 5; gather now reads bf16 channels-last xtr).
// ---------------------------------------------------------------------------
__global__ __launch_bounds__(256, 2) void dcn_mfma(
    const ushortT* __restrict__ xtr,   // bf16 channels-last input_real
    const float* __restrict__ off,     // [B][18][HoWo]
    const float* __restrict__ mask,    // [B][9][HoWo]
    const ushortT* __restrict__ Whi,   // [64][576] bf16
    const ushortT* __restrict__ Wlo,   // [64][576] bf16
    const float* __restrict__ bd,      // [64]
    float* __restrict__ out)           // [B][64][HoWo]
{
    __shared__ ushortT vlds[64 * 576];   // 72 KB, row = pix (1152 B)
    __shared__ float offm[64][28];       // 7 KB

    const int tid = threadIdx.x;
    const int p0  = blockIdx.x * 64;
    const int b   = p0 >> 14;
    const int pl  = p0 & 16383;

    for (int it = tid; it < 64 * 27; it += 256) {
        const int pp = it & 63;
        const int o  = it >> 6;
        offm[pp][o] = (o < 18)
            ? off[(b * 18 + o) * HOWO + pl + pp]
            : mask[(b * 9 + (o - 18)) * HOWO + pl + pp];
    }
    __syncthreads();

    // ---- gather: 576 tasks (pix,kk), 8 threads/task, bf16 corners
    {
        const int s    = tid & 7;
        const int ch0  = s << 3;
        const int bofs = b << 14;
#pragma unroll 2
        for (int rnd = 0; rnd < 18; ++rnd) {
            const int task = rnd * 32 + (tid >> 3);
            const int pix  = task & 63;
            const int kk   = task >> 6;
            const int pg   = pl + pix;
            const int ho   = pg >> 7, wo = pg & 127;
            const int ky   = kk / 3, kx = kk - 3 * ky;

            float w00, w01, w10, w11; int i00, i01, i10, i11;
            bilinear_params(offm[pix][2 * kk], offm[pix][2 * kk + 1],
                            offm[pix][18 + kk], ho, wo, ky, kx,
                            w00, w01, w10, w11, i00, i01, i10, i11);

            const short8v r00 = *(const short8v*)(xtr + ((size_t)(bofs + i00) << 6) + ch0);
            const short8v r01 = *(const short8v*)(xtr + ((size_t)(bofs + i01) << 6) + ch0);
            const short8v r10 = *(const short8v*)(xtr + ((size_t)(bofs + i10) << 6) + ch0);
            const short8v r11 = *(const short8v*)(xtr + ((size_t)(bofs + i11) << 6) + ch0);

            short8v pk;
#pragma unroll
            for (int j = 0; j < 8; ++j) {
                const float v = w00 * bf2f((ushortT)r00[j]) +
                                w01 * bf2f((ushortT)r01[j]) +
                                w10 * bf2f((ushortT)r10[j]) +
                                w11 * bf2f((ushortT)r11[j]);
                pk[j] = (short)f2bf(v);
            }

            // byte(k,pix) = pix*1152 + ((2k) ^ ((pix&7)<<4)), k = kk*64+ch0
            const int inrow = (((kk << 6) + ch0) << 1) ^ ((pix & 7) << 4);
            *(short8v*)((char*)vlds + pix * 1152 + inrow) = pk;
        }
    }
    __syncthreads();

    // ---- GEMM phase (verified layout)
    {
        const int lane = tid & 63;
        const int wid  = tid >> 6;
        const int l15  = lane & 15;
        const int l4   = lane >> 4;
        const int oc0  = wid << 4;

        const ushortT* whiRow = Whi + (oc0 + l15) * 576 + (l4 << 3);
        const ushortT* wloRow = Wlo + (oc0 + l15) * 576 + (l4 << 3);
        const int swz = (l15 & 7) << 4;
        const int kl  = l4 << 4;

        f32x4 ac0 = {0.f, 0.f, 0.f, 0.f};
        f32x4 ac1 = {0.f, 0.f, 0.f, 0.f};
        f32x4 ac2 = {0.f, 0.f, 0.f, 0.f};
        f32x4 ac3 = {0.f, 0.f, 0.f, 0.f};

#pragma unroll
        for (int ks = 0; ks < 18; ++ks) {
            const int k0 = ks * 32;
            const short8v ahi = *(const short8v*)(whiRow + k0);
            const short8v alo = *(const short8v*)(wloRow + k0);
            const int inrow = ((k0 << 1) + kl) ^ swz;
            const char* base = (const char*)vlds + inrow;
            const short8v b0 = *(const short8v*)(base + (l15 + 0)  * 1152);
            const short8v b1 = *(const short8v*)(base + (l15 + 16) * 1152);
            const short8v b2 = *(const short8v*)(base + (l15 + 32) * 1152);
            const short8v b3 = *(const short8v*)(base + (l15 + 48) * 1152);
            ac0 = __builtin_amdgcn_mfma_f32_16x16x32_bf16(ahi, b0, ac0, 0, 0, 0);
            ac0 = __builtin_amdgcn_mfma_f32_16x16x32_bf16(alo, b0, ac0, 0, 0, 0);
            ac1 = __builtin_amdgcn_mfma_f32_16x16x32_bf16(ahi, b1, ac1, 0, 0, 0);
            ac1 = __builtin_amdgcn_mfma_f32_16x16x32_bf16(alo, b1, ac1, 0, 0, 0);
            ac2 = __builtin_amdgcn_mfma_f32_16x16x32_bf16(ahi, b2, ac2, 0, 0, 0);
            ac2 = __builtin_amdgcn_mfma_f32_16x16x32_bf16(alo, b2, ac2, 0, 0, 0);
            ac3 = __builtin_amdgcn_mfma_f32_16x16x32_bf16(ahi, b3, ac3, 0, 0, 0);
            ac3 = __builtin_amdgcn_mfma_f32_16x16x32_bf16(alo, b3, ac3, 0, 0, 0);
        }

#pragma unroll
        for (int r = 0; r < 4; ++r) {
            const int oc = oc0 + (l4 << 2) + r;
            const float bias = bd[oc];
            const size_t ob = ((size_t)(b * OO + oc)) * HOWO + pl + l15;
            out[ob + 0]  = ac0[r] + bias;
            out[ob + 16] = ac1[r] + bias;
            out[ob + 32] = ac2[r] + bias;
            out[ob + 48] = ac3[r] + bias;
        }
    }
}

// ---------------------------------------------------------------------------
// Mid tier (round-4, proven): prep_transpose + conv_om2 + dcn2
// ---------------------------------------------------------------------------
__global__ __launch_bounds__(256) void prep_transpose(
    const float* __restrict__ w_dcn, const float* __restrict__ w_om,
    float* __restrict__ wt_dcn, float* __restrict__ wt_om)
{
    int idx = blockIdx.x * 256 + threadIdx.x;
    if (idx < 9 * 64 * 64) {
        int o  = idx & 63;
        int c  = (idx >> 6) & 63;
        int kk = idx >> 12;
        wt_dcn[idx] = w_dcn[(o * CC + c) * 9 + kk];
    }
    if (idx < 9 * 64 * 28) {
        int o    = idx % 28;
        int rest = idx / 28;
        int c    = rest & 63;
        int kk   = rest >> 6;
        wt_om[idx] = (o < OMC) ? w_om[(o * CC + c) * 9 + kk] : 0.f;
    }
}

__global__ __launch_bounds__(256) void conv_om2(
    const float* __restrict__ x, const float* __restrict__ wtom,
    const float* __restrict__ bom, float* __restrict__ off_out,
    float* __restrict__ mask_out)
{
    const int pg  = blockIdx.x * 256 + threadIdx.x;
    const int b   = pg >> 14;
    const int p   = pg & 16383;
    const int ho  = p >> 7, wo = p & 127;
    const int oc0 = blockIdx.y << 3;

    float acc[8];
#pragma unroll
    for (int j = 0; j < 8; ++j) acc[j] = 0.f;

    const float* xb = x + (size_t)b * CC * HWSZ;
    for (int c = 0; c < CC; ++c) {
        const float* xc = xb + c * HWSZ;
        float t[9];
#pragma unroll
        for (int kh = 0; kh < 3; ++kh) {
            const int ih = ho + kh - 1;
            const bool rv = (unsigned)ih < (unsigned)HH;
#pragma unroll
            for (int kw = 0; kw < 3; ++kw) {
                const int iw = wo + kw - 1;
                t[kh * 3 + kw] =
                    (rv && (unsigned)iw < (unsigned)WW) ? xc[ih * WW + iw] : 0.f;
            }
        }
#pragma unroll
        for (int kk = 0; kk < 9; ++kk) {
            const float tv = t[kk];
            const float4* wr = (const float4*)(wtom + ((kk << 6) + c) * 28 + oc0);
            const float4 w0 = wr[0];
            const float4 w1 = wr[1];
            acc[0] += tv * w0.x; acc[1] += tv * w0.y;
            acc[2] += tv * w0.z; acc[3] += tv * w0.w;
            acc[4] += tv * w1.x; acc[5] += tv * w1.y;
            acc[6] += tv * w1.z; acc[7] += tv * w1.w;
        }
    }
#pragma unroll
    for (int j = 0; j < 8; ++j) {
        const int oc = oc0 + j;
        if (oc < 18) {
            off_out[(b * 18 + oc) * HOWO + p] = acc[j] + bom[oc];
        } else if (oc < OMC) {
            mask_out[(b * 9 + (oc - 18)) * HOWO + p] =
                1.f / (1.f + expf(-(acc[j] + bom[oc])));
        }
    }
}

__global__ __launch_bounds__(256) void dcn2(
    const float* __restrict__ xr, const float* __restrict__ off,
    const float* __restrict__ mask, const float* __restrict__ wtd,
    const float* __restrict__ bd, float* __restrict__ out)
{
    __shared__ float offm[32][29];
    __shared__ float vtile[64 * 33];

    const int tid  = threadIdx.x;
    const int pixl = tid & 31;
    const int grp  = tid >> 5;
    const int p0g  = blockIdx.x * 32;
    const int b    = p0g >> 14;
    const int p0   = p0g & 16383;
    const int p    = p0 + pixl;
    const int ho   = p >> 7, wo = p & 127;

    for (int it = tid; it < 32 * 27; it += 256) {
        const int pp = it & 31;
        const int o  = it >> 5;
        offm[pp][o] = (o < 18)
            ? off[(b * 18 + o) * HOWO + p0 + pp]
            : mask[(b * 9 + (o - 18)) * HOWO + p0 + pp];
    }
    __syncthreads();

    float acc[8];
#pragma unroll
    for (int j = 0; j < 8; ++j) acc[j] = 0.f;

    const float* xrb = xr + (size_t)b * CC * HWSZ;

    for (int kk = 0; kk < 9; ++kk) {
        {
            const int ky = kk / 3, kx = kk - ky * 3;
            float w00, w01, w10, w11; int i00, i01, i10, i11;
            bilinear_params(offm[pixl][2 * kk], offm[pixl][2 * kk + 1],
                            offm[pixl][18 + kk], ho, wo, ky, kx,
                            w00, w01, w10, w11, i00, i01, i10, i11);
            const float* xg = xrb + (grp << 3) * HWSZ;
#pragma unroll
            for (int i = 0; i < 8; ++i) {
                const float* xc = xg + i * HWSZ;
                const float v = w00 * xc[i00] + w01 * xc[i01] +
                                w10 * xc[i10] + w11 * xc[i11];
                vtile[((grp << 3) + i) * 33 + pixl] = v;
            }
        }
        __syncthreads();

        const float* wk = wtd + (kk << 12) + (grp << 3);
#pragma unroll 8
        for (int c = 0; c < 64; ++c) {
            const float v = vtile[c * 33 + pixl];
            const float4* wr = (const float4*)(wk + (c << 6));
            const float4 w0 = wr[0];
            const float4 w1 = wr[1];
            acc[0] += v * w0.x; acc[1] += v * w0.y;
            acc[2] += v * w0.z; acc[3] += v * w0.w;
            acc[4] += v * w1.x; acc[5] += v * w1.y;
            acc[6] += v * w1.z; acc[7] += v * w1.w;
        }
        __syncthreads();
    }

#pragma unroll
    for (int q = 0; q < 8; ++q) {
        const int oc = (grp << 3) + q;
        out[((size_t)(b * OO + oc)) * HOWO + p0 + pixl] = acc[q] + bd[oc];
    }
}

// ---------------------------------------------------------------------------
// Slow fallback (round-0, verified)
// ---------------------------------------------------------------------------
__global__ __launch_bounds__(256) void conv_om_slow(
    const float* __restrict__ x, const float* __restrict__ w,
    const float* __restrict__ bias, float* __restrict__ off_out)
{
    const int xid = blockIdx.x;
    const int b   = xid >> 6;
    const int p   = ((xid & 63) << 8) + threadIdx.x;
    const int ho  = p >> 7, wo = p & 127;
    const int oc0 = blockIdx.y << 4;

    float acc[16];
#pragma unroll
    for (int j = 0; j < 16; ++j) {
        const int oc = oc0 + j;
        acc[j] = (oc < OMC) ? bias[oc] : 0.f;
    }
    const float* xb = x + (size_t)b * CC * HWSZ;
    for (int c = 0; c < CC; ++c) {
        const float* xc = xb + c * HWSZ;
        float t[9];
#pragma unroll
        for (int kh = 0; kh < 3; ++kh) {
            const int ih = ho + kh - 1;
            const bool rv = (unsigned)ih < (unsigned)HH;
#pragma unroll
            for (int kw = 0; kw < 3; ++kw) {
                const int iw = wo + kw - 1;
                t[kh * 3 + kw] =
                    (rv && (unsigned)iw < (unsigned)WW) ? xc[ih * WW + iw] : 0.f;
            }
        }
#pragma unroll
        for (int j = 0; j < 16; ++j) {
            const int oc = oc0 + j;
            if (oc < OMC) {
                const float* wj = w + (size_t)(oc * CC + c) * 9;
                float s = 0.f;
#pragma unroll
                for (int kk = 0; kk < 9; ++kk) s += t[kk] * wj[kk];
                acc[j] += s;
            }
        }
    }
#pragma unroll
    for (int j = 0; j < 16; ++j) {
        const int oc = oc0 + j;
        if (oc < 18) off_out[(b * 18 + oc) * HOWO + p] = acc[j];
    }
}

__global__ __launch_bounds__(256) void dcn_slow(
    const float* __restrict__ xr, const float* __restrict__ off,
    const float* __restrict__ wd, const float* __restrict__ bd,
    float* __restrict__ out, const float* __restrict__ xo,
    const float* __restrict__ wom, const float* __restrict__ bom)
{
    const int xid = blockIdx.x;
    const int b   = xid >> 6;
    const int p   = ((xid & 63) << 8) + threadIdx.x;
    const int ho  = p >> 7, wo = p & 127;
    const int o0  = blockIdx.y << 4;

    float acc[16];
#pragma unroll
    for (int j = 0; j < 16; ++j) acc[j] = bd[o0 + j];
    const float* xb = xr + (size_t)b * CC * HWSZ;

    for (int kk = 0; kk < 9; ++kk) {
        const float oy = off[(b * 18 + 2 * kk) * HOWO + p];
        const float ox = off[(b * 18 + 2 * kk + 1) * HOWO + p];
        float a = bom[18 + kk];
        const float* xob = xo + (size_t)b * CC * HWSZ;
        for (int c = 0; c < CC; ++c) {
            const float* xc2 = xob + c * HWSZ;
            const float* wj  = wom + (size_t)((18 + kk) * CC + c) * 9;
#pragma unroll
            for (int kh = 0; kh < 3; ++kh) {
                const int ih = ho + kh - 1;
                if ((unsigned)ih < (unsigned)HH) {
#pragma unroll
                    for (int kw = 0; kw < 3; ++kw) {
                        const int iw = wo + kw - 1;
                        if ((unsigned)iw < (unsigned)WW)
                            a += xc2[ih * WW + iw] * wj[kh * 3 + kw];
                    }
                }
            }
        }
        const float m = 1.f / (1.f + expf(-a));
        const int ky = kk / 3, kx = kk - ky * 3;
        float w00, w01, w10, w11; int i00, i01, i10, i11;
        bilinear_params(oy, ox, m, ho, wo, ky, kx,
                        w00, w01, w10, w11, i00, i01, i10, i11);
#pragma unroll 4
        for (int c = 0; c < CC; ++c) {
            const float* xc = xb + c * HWSZ;
            const float v = w00 * xc[i00] + w01 * xc[i01] +
                            w10 * xc[i10] + w11 * xc[i11];
#pragma unroll
            for (int j = 0; j < 16; ++j)
                acc[j] += v * wd[(size_t)((o0 + j) * CC + c) * 9 + kk];
        }
    }
#pragma unroll
    for (int j = 0; j < 16; ++j)
        out[((size_t)b * OO + o0 + j) * HOWO + p] = acc[j];
}

// ---------------------------------------------------------------------------
extern "C" void kernel_launch(void* const* d_in, const int* in_sizes, int n_in,
                              void* d_out, int out_size, void* d_ws, size_t ws_size,
                              hipStream_t stream)
{
    const float* x_off  = (const float*)d_in[0];
    const float* x_real = (const float*)d_in[1];
    const float* w_om   = (const float*)d_in[2];
    const float* b_om   = (const float*)d_in[3];
    const float* w_dcn  = (const float*)d_in[4];
    const float* b_dcn  = (const float*)d_in[5];

    float* out = (float*)d_out;
    const int outElems = BB * OO * HOWO;
    float* off_out = out + outElems;                  // [B][18][HoWo]

    // Full-tier layout (9,789,440 B — less than round-5's proven 9,927,680)
    const size_t maskB   = (size_t)BB * 9 * HOWO * 4;     // 1,179,648
    const size_t xtB     = (size_t)BB * HWSZ * CC * 2;    // 4,194,304 each
    const size_t wSplitB = (size_t)64 * 576 * 2;          // 73,728 each
    const size_t womB    = (size_t)32 * 576 * 2;          // 36,864 each
    const size_t need_full = maskB + 2 * xtB + 2 * wSplitB + 2 * womB;

    const size_t wtDcnF = 9 * 64 * 64;
    const size_t wtOmF  = 9 * 64 * 28;
    const size_t need_mid = (wtDcnF + wtOmF + (size_t)BB * 9 * HOWO) * 4;

    if (ws_size >= need_full) {
        char* w = (char*)d_ws;
        float*   maskBuf = (float*)w;        w += maskB;
        ushortT* xtr     = (ushortT*)w;      w += xtB;
        ushortT* xto     = (ushortT*)w;      w += xtB;
        ushortT* Whi     = (ushortT*)w;      w += wSplitB;
        ushortT* Wlo     = (ushortT*)w;      w += wSplitB;
        ushortT* Womhi   = (ushortT*)w;      w += womB;
        ushortT* Womlo   = (ushortT*)w;

        hipLaunchKernelGGL(prep2, dim3(144), dim3(256), 0, stream,
                           w_dcn, w_om, Whi, Wlo, Womhi, Womlo);
        hipLaunchKernelGGL(xtpose2, dim3(BB * HH, 2), dim3(256), 0, stream,
                           x_real, x_off, xtr, xto);
        hipLaunchKernelGGL(conv_om_mfma, dim3(512), dim3(256), 0, stream,
                           xto, Womhi, Womlo, b_om, off_out, maskBuf);
        hipLaunchKernelGGL(dcn_mfma, dim3(512), dim3(256), 0, stream,
                           xtr, off_out, maskBuf, Whi, Wlo, b_dcn, out);
    } else if (ws_size >= need_mid) {
        float* wtDcn   = (float*)d_ws;
        float* wtOm    = wtDcn + wtDcnF;
        float* maskBuf = wtOm + wtOmF;
        hipLaunchKernelGGL(prep_transpose, dim3(144), dim3(256), 0, stream,
                           w_dcn, w_om, wtDcn, wtOm);
        hipLaunchKernelGGL(conv_om2, dim3(128, 4), dim3(256), 0, stream,
                           x_off, wtOm, b_om, off_out, maskBuf);
        hipLaunchKernelGGL(dcn2, dim3(1024), dim3(256), 0, stream,
                           x_real, off_out, maskBuf, wtDcn, b_dcn, out);
    } else {
        hipLaunchKernelGGL(conv_om_slow, dim3(128, 2), dim3(256), 0, stream,
                           x_off, w_om, b_om, off_out);
        hipLaunchKernelGGL(dcn_slow, dim3(128, 4), dim3(256), 0, stream,
                           x_real, off_out, w_dcn, b_dcn, out,
                           x_off, w_om, b_om);
    }
}

// Round 7
// 53.923 us; speedup vs baseline: 12.0629x; 1.1612x over previous
//
#include <hip/hip_runtime.h>
#include <math.h>

constexpr int BB   = 2;
constexpr int CC   = 64;
constexpr int HH   = 128;
constexpr int WW   = 128;
constexpr int OO   = 64;
constexpr int HWSZ = HH * WW;    // 16384
constexpr int HOWO = 16384;
constexpr int OMC  = 27;

typedef __attribute__((ext_vector_type(8))) short short8v;  // 8 bf16
typedef __attribute__((ext_vector_type(4))) float f32x4;
typedef unsigned short ushortT;

__device__ __forceinline__ ushortT f2bf(float x) {
    unsigned int u = __builtin_bit_cast(unsigned int, x);
    u = (u + 0x7FFFu + ((u >> 16) & 1u)) >> 16;   // RTNE
    return (ushortT)u;
}
__device__ __forceinline__ float bf2f(ushortT u) {
    return __builtin_bit_cast(float, (unsigned int)u << 16);
}

// ---------------------------------------------------------------------------
// xtpose_prep: blocks 0..511 transpose NCHW fp32 -> channels-last bf16
// (0..255: input_real -> xtr, 256..511: input_offset -> xto);
// blocks 512..655 build Whi/Wlo [64][576] and Womhi/Womlo [32][576] bf16.
// ---------------------------------------------------------------------------
__global__ __launch_bounds__(256) void xtpose_prep(
    const float* __restrict__ xr, const float* __restrict__ xo,
    ushortT* __restrict__ xtr, ushortT* __restrict__ xto,
    const float* __restrict__ w_dcn, const float* __restrict__ w_om,
    ushortT* __restrict__ Whi, ushortT* __restrict__ Wlo,
    ushortT* __restrict__ Womhi, ushortT* __restrict__ Womlo)
{
    __shared__ float t[64][129];
    const int tid = threadIdx.x;
    const int bid = blockIdx.x;

    if (bid < 512) {
        const int by = bid & 255;            // b*128 + y
        const int b  = by >> 7, y = by & 127;
        const float* src = (bid < 256) ? xr : xo;
        ushortT*    dst  = (bid < 256) ? xtr : xto;

#pragma unroll
        for (int cc = 0; cc < 64; cc += 2) {
            const int c  = cc + (tid >> 7);
            const int xw = tid & 127;
            t[c][xw] = src[((size_t)(b * 64 + c) * 128 + y) * 128 + xw];
        }
        __syncthreads();

#pragma unroll
        for (int r = 0; r < 8; ++r) {
            const int idx = r * 256 + tid;
            const int xw  = idx >> 4;
            const int cq  = (idx & 15) << 2;
            ushort4 pk = make_ushort4(f2bf(t[cq][xw]), f2bf(t[cq + 1][xw]),
                                      f2bf(t[cq + 2][xw]), f2bf(t[cq + 3][xw]));
            *(ushort4*)(dst + (((size_t)by * 128 + xw) << 6) + cq) = pk;
        }
    } else {
        const int idx = (bid - 512) * 256 + tid;
        if (idx < 64 * 576) {
            int o  = idx / 576;
            int k  = idx - o * 576;
            int kk = k >> 6;
            int c  = k & 63;
            float w = w_dcn[(o * CC + c) * 9 + kk];
            ushortT hi = f2bf(w);
            Whi[idx] = hi;
            Wlo[idx] = f2bf(w - bf2f(hi));
        }
        if (idx < 32 * 576) {
            int o  = idx / 576;
            int k  = idx - o * 576;
            int kk = k >> 6;
            int c  = k & 63;
            float w = (o < OMC) ? w_om[(o * CC + c) * 9 + kk] : 0.f;
            ushortT hi = f2bf(w);
            Womhi[idx] = hi;
            Womlo[idx] = f2bf(w - bf2f(hi));
        }
    }
}

__device__ __forceinline__ void bilinear_params(
    float oy, float ox, float m, int ho, int wo, int ky, int kx,
    float& w00, float& w01, float& w10, float& w11,
    int& i00, int& i01, int& i10, int& i11)
{
    const float yf = (float)(ho + ky - 1) + oy;
    const float xf = (float)(wo + kx - 1) + ox;
    const float y0 = floorf(yf), x0 = floorf(xf);
    const float ly = yf - y0, lx = xf - x0;
    const float hy = 1.f - ly, hx = 1.f - lx;
    const int iy0 = (int)y0, ix0 = (int)x0;
    const int iy1 = iy0 + 1, ix1 = ix0 + 1;
    const bool vy0 = (unsigned)iy0 < (unsigned)HH;
    const bool vy1 = (unsigned)iy1 < (unsigned)HH;
    const bool vx0 = (unsigned)ix0 < (unsigned)WW;
    const bool vx1 = (unsigned)ix1 < (unsigned)WW;
    w00 = (vy0 && vx0) ? hy * hx * m : 0.f;
    w01 = (vy0 && vx1) ? hy * lx * m : 0.f;
    w10 = (vy1 && vx0) ? ly * hx * m : 0.f;
    w11 = (vy1 && vx1) ? ly * lx * m : 0.f;
    const int cy0 = min(max(iy0, 0), HH - 1), cy1 = min(max(iy1, 0), HH - 1);
    const int cx0 = min(max(ix0, 0), WW - 1), cx1 = min(max(ix1, 0), WW - 1);
    i00 = cy0 * WW + cx0; i01 = cy0 * WW + cx1;
    i10 = cy1 * WW + cx0; i11 = cy1 * WW + cx1;
}

// ---------------------------------------------------------------------------
// fused_all: block = 64 pixels, 256 threads (4 waves).
// Phase 0: offset/mask conv via MFMA (verified round-6 mapping) ->
//          offsets to d_out + offm LDS; sigmoid mask to offm only.
// Phases 1..3: K chunked 3x(3 kk = 192 k): gather bf16 V into 24 KB
//          swizzled vlds -> barrier -> 6 MFMA k-steps -> barrier.
// Fragment/swizzle math identical to verified round-5/6 kernels
// (row stride 384 B ~ 1152 B: both = 0 mod 128 B).
// ---------------------------------------------------------------------------
__global__ __launch_bounds__(256, 3) void fused_all(
    const ushortT* __restrict__ xtr,    // bf16 channels-last input_real
    const ushortT* __restrict__ xto,    // bf16 channels-last input_offset
    const ushortT* __restrict__ Womhi,  // [32][576]
    const ushortT* __restrict__ Womlo,
    const float* __restrict__ bom,      // [27]
    const ushortT* __restrict__ Whi,    // [64][576]
    const ushortT* __restrict__ Wlo,
    const float* __restrict__ bd,       // [64]
    float* __restrict__ out,            // [B][64][HoWo]
    float* __restrict__ off_out)        // [B][18][HoWo]
{
    __shared__ ushortT vlds[64 * 192];   // 24 KB, row = pix (384 B)
    __shared__ float offm[64][28];       // 7 KB

    const int tid  = threadIdx.x;
    const int lane = tid & 63;
    const int wid  = tid >> 6;
    const int l15  = lane & 15;
    const int l4   = lane >> 4;
    const int p0   = blockIdx.x * 64;
    const int b    = p0 >> 14;
    const int pl   = p0 & 16383;
    const size_t bbase = (size_t)(b << 14);

    // ---------------- Phase 0: offset/mask conv (verified mapping)
    {
        const int lpix = (wid << 4) + l15;
        const int pix  = pl + lpix;
        const int ho   = pix >> 7, wo = pix & 127;
        f32x4 acc0 = {0.f, 0.f, 0.f, 0.f};
        f32x4 acc1 = {0.f, 0.f, 0.f, 0.f};
        const ushortT* wh = Womhi + l15 * 576 + (l4 << 3);
        const ushortT* wl = Womlo + l15 * 576 + (l4 << 3);
        const short8v zero8 = {0, 0, 0, 0, 0, 0, 0, 0};

#pragma unroll
        for (int ks = 0; ks < 18; ++ks) {
            const int kk = ks >> 1;
            const int ky = kk / 3, kx = kk - 3 * ky;
            const int iy = ho + ky - 1, ix = wo + kx - 1;
            const bool valid = ((unsigned)iy < 128u) && ((unsigned)ix < 128u);
            const int cy = min(max(iy, 0), 127), cx = min(max(ix, 0), 127);
            const int c0 = ((ks & 1) << 5) + (l4 << 3);
            const short8v braw =
                *(const short8v*)(xto + ((bbase + cy * 128 + cx) << 6) + c0);
            const short8v bf = valid ? braw : zero8;

            const int k0 = ks << 5;
            const short8v ah0 = *(const short8v*)(wh + k0);
            const short8v al0 = *(const short8v*)(wl + k0);
            const short8v ah1 = *(const short8v*)(wh + 16 * 576 + k0);
            const short8v al1 = *(const short8v*)(wl + 16 * 576 + k0);
            acc0 = __builtin_amdgcn_mfma_f32_16x16x32_bf16(ah0, bf, acc0, 0, 0, 0);
            acc0 = __builtin_amdgcn_mfma_f32_16x16x32_bf16(al0, bf, acc0, 0, 0, 0);
            acc1 = __builtin_amdgcn_mfma_f32_16x16x32_bf16(ah1, bf, acc1, 0, 0, 0);
            acc1 = __builtin_amdgcn_mfma_f32_16x16x32_bf16(al1, bf, acc1, 0, 0, 0);
        }

#pragma unroll
        for (int r = 0; r < 4; ++r) {
            const int oca = (l4 << 2) + r;            // 0..15 -> offset
            const float va = acc0[r] + bom[oca];
            offm[lpix][oca] = va;
            off_out[(b * 18 + oca) * HOWO + pix] = va;
            const int ocb = 16 + (l4 << 2) + r;       // 16..31
            if (ocb < 18) {
                const float vb = acc1[r] + bom[ocb];
                offm[lpix][ocb] = vb;
                off_out[(b * 18 + ocb) * HOWO + pix] = vb;
            } else if (ocb < OMC) {
                offm[lpix][ocb] = 1.f / (1.f + expf(-(acc1[r] + bom[ocb])));
            }
        }
    }
    __syncthreads();

    // ---------------- Phases 1..3: chunked gather + GEMM
    f32x4 ac0 = {0.f, 0.f, 0.f, 0.f};
    f32x4 ac1 = {0.f, 0.f, 0.f, 0.f};
    f32x4 ac2 = {0.f, 0.f, 0.f, 0.f};
    f32x4 ac3 = {0.f, 0.f, 0.f, 0.f};

    const ushortT* whiRow = Whi + ((wid << 4) + l15) * 576 + (l4 << 3);
    const ushortT* wloRow = Wlo + ((wid << 4) + l15) * 576 + (l4 << 3);
    const int swz = (l15 & 7) << 4;
    const int s   = tid & 7;
    const int ch0 = s << 3;

#pragma unroll 1
    for (int ck = 0; ck < 3; ++ck) {
        const int kk0 = ck * 3;

        // gather: 192 tasks (pix, kkl), 8 threads/task, 6 rounds
#pragma unroll 2
        for (int rnd = 0; rnd < 6; ++rnd) {
            const int task = rnd * 32 + (tid >> 3);
            const int pix  = task & 63;
            const int kkl  = task >> 6;          // 0..2
            const int kk   = kk0 + kkl;
            const int pg   = pl + pix;
            const int ho   = pg >> 7, wo = pg & 127;
            const int ky   = kk / 3, kx = kk - 3 * ky;

            float w00, w01, w10, w11; int i00, i01, i10, i11;
            bilinear_params(offm[pix][2 * kk], offm[pix][2 * kk + 1],
                            offm[pix][18 + kk], ho, wo, ky, kx,
                            w00, w01, w10, w11, i00, i01, i10, i11);

            const short8v r00 = *(const short8v*)(xtr + ((bbase + i00) << 6) + ch0);
            const short8v r01 = *(const short8v*)(xtr + ((bbase + i01) << 6) + ch0);
            const short8v r10 = *(const short8v*)(xtr + ((bbase + i10) << 6) + ch0);
            const short8v r11 = *(const short8v*)(xtr + ((bbase + i11) << 6) + ch0);

            short8v pk;
#pragma unroll
            for (int j = 0; j < 8; ++j) {
                const float v = w00 * bf2f((ushortT)r00[j]) +
                                w01 * bf2f((ushortT)r01[j]) +
                                w10 * bf2f((ushortT)r10[j]) +
                                w11 * bf2f((ushortT)r11[j]);
                pk[j] = (short)f2bf(v);
            }

            // byte(k_local,pix) = pix*384 + ((2*k_local) ^ ((pix&7)<<4))
            const int inrow = (((kkl << 6) + ch0) << 1) ^ ((pix & 7) << 4);
            *(short8v*)((char*)vlds + pix * 384 + inrow) = pk;
        }
        __syncthreads();

        // GEMM: 6 k-steps of 32 over this chunk
#pragma unroll
        for (int ksl = 0; ksl < 6; ++ksl) {
            const int kg = ck * 192 + ksl * 32;           // global k (weights)
            const short8v ahi = *(const short8v*)(whiRow + kg);
            const short8v alo = *(const short8v*)(wloRow + kg);
            const int inrow = ((ksl << 6) + (l4 << 4)) ^ swz;   // local bytes
            const char* base = (const char*)vlds + inrow;
            const short8v b0 = *(const short8v*)(base + (l15 + 0)  * 384);
            const short8v b1 = *(const short8v*)(base + (l15 + 16) * 384);
            const short8v b2 = *(const short8v*)(base + (l15 + 32) * 384);
            const short8v b3 = *(const short8v*)(base + (l15 + 48) * 384);
            ac0 = __builtin_amdgcn_mfma_f32_16x16x32_bf16(ahi, b0, ac0, 0, 0, 0);
            ac0 = __builtin_amdgcn_mfma_f32_16x16x32_bf16(alo, b0, ac0, 0, 0, 0);
            ac1 = __builtin_amdgcn_mfma_f32_16x16x32_bf16(ahi, b1, ac1, 0, 0, 0);
            ac1 = __builtin_amdgcn_mfma_f32_16x16x32_bf16(alo, b1, ac1, 0, 0, 0);
            ac2 = __builtin_amdgcn_mfma_f32_16x16x32_bf16(ahi, b2, ac2, 0, 0, 0);
            ac2 = __builtin_amdgcn_mfma_f32_16x16x32_bf16(alo, b2, ac2, 0, 0, 0);
            ac3 = __builtin_amdgcn_mfma_f32_16x16x32_bf16(ahi, b3, ac3, 0, 0, 0);
            ac3 = __builtin_amdgcn_mfma_f32_16x16x32_bf16(alo, b3, ac3, 0, 0, 0);
        }
        __syncthreads();
    }

    // ---------------- epilogue (verified C/D mapping)
#pragma unroll
    for (int r = 0; r < 4; ++r) {
        const int oc = (wid << 4) + (l4 << 2) + r;
        const float bias = bd[oc];
        const size_t ob = ((size_t)(b * OO + oc)) * HOWO + pl + l15;
        out[ob + 0]  = ac0[r] + bias;
        out[ob + 16] = ac1[r] + bias;
        out[ob + 32] = ac2[r] + bias;
        out[ob + 48] = ac3[r] + bias;
    }
}

// ---------------------------------------------------------------------------
// Mid tier (round-4, proven)
// ---------------------------------------------------------------------------
__global__ __launch_bounds__(256) void prep_transpose(
    const float* __restrict__ w_dcn, const float* __restrict__ w_om,
    float* __restrict__ wt_dcn, float* __restrict__ wt_om)
{
    int idx = blockIdx.x * 256 + threadIdx.x;
    if (idx < 9 * 64 * 64) {
        int o  = idx & 63;
        int c  = (idx >> 6) & 63;
        int kk = idx >> 12;
        wt_dcn[idx] = w_dcn[(o * CC + c) * 9 + kk];
    }
    if (idx < 9 * 64 * 28) {
        int o    = idx % 28;
        int rest = idx / 28;
        int c    = rest & 63;
        int kk   = rest >> 6;
        wt_om[idx] = (o < OMC) ? w_om[(o * CC + c) * 9 + kk] : 0.f;
    }
}

__global__ __launch_bounds__(256) void conv_om2(
    const float* __restrict__ x, const float* __restrict__ wtom,
    const float* __restrict__ bom, float* __restrict__ off_out,
    float* __restrict__ mask_out)
{
    const int pg  = blockIdx.x * 256 + threadIdx.x;
    const int b   = pg >> 14;
    const int p   = pg & 16383;
    const int ho  = p >> 7, wo = p & 127;
    const int oc0 = blockIdx.y << 3;

    float acc[8];
#pragma unroll
    for (int j = 0; j < 8; ++j) acc[j] = 0.f;

    const float* xb = x + (size_t)b * CC * HWSZ;
    for (int c = 0; c < CC; ++c) {
        const float* xc = xb + c * HWSZ;
        float t[9];
#pragma unroll
        for (int kh = 0; kh < 3; ++kh) {
            const int ih = ho + kh - 1;
            const bool rv = (unsigned)ih < (unsigned)HH;
#pragma unroll
            for (int kw = 0; kw < 3; ++kw) {
                const int iw = wo + kw - 1;
                t[kh * 3 + kw] =
                    (rv && (unsigned)iw < (unsigned)WW) ? xc[ih * WW + iw] : 0.f;
            }
        }
#pragma unroll
        for (int kk = 0; kk < 9; ++kk) {
            const float tv = t[kk];
            const float4* wr = (const float4*)(wtom + ((kk << 6) + c) * 28 + oc0);
            const float4 w0 = wr[0];
            const float4 w1 = wr[1];
            acc[0] += tv * w0.x; acc[1] += tv * w0.y;
            acc[2] += tv * w0.z; acc[3] += tv * w0.w;
            acc[4] += tv * w1.x; acc[5] += tv * w1.y;
            acc[6] += tv * w1.z; acc[7] += tv * w1.w;
        }
    }
#pragma unroll
    for (int j = 0; j < 8; ++j) {
        const int oc = oc0 + j;
        if (oc < 18) {
            off_out[(b * 18 + oc) * HOWO + p] = acc[j] + bom[oc];
        } else if (oc < OMC) {
            mask_out[(b * 9 + (oc - 18)) * HOWO + p] =
                1.f / (1.f + expf(-(acc[j] + bom[oc])));
        }
    }
}

__global__ __launch_bounds__(256) void dcn2(
    const float* __restrict__ xr, const float* __restrict__ off,
    const float* __restrict__ mask, const float* __restrict__ wtd,
    const float* __restrict__ bd, float* __restrict__ out)
{
    __shared__ float offm[32][29];
    __shared__ float vtile[64 * 33];

    const int tid  = threadIdx.x;
    const int pixl = tid & 31;
    const int grp  = tid >> 5;
    const int p0g  = blockIdx.x * 32;
    const int b    = p0g >> 14;
    const int p0   = p0g & 16383;
    const int p    = p0 + pixl;
    const int ho   = p >> 7, wo = p & 127;

    for (int it = tid; it < 32 * 27; it += 256) {
        const int pp = it & 31;
        const int o  = it >> 5;
        offm[pp][o] = (o < 18)
            ? off[(b * 18 + o) * HOWO + p0 + pp]
            : mask[(b * 9 + (o - 18)) * HOWO + p0 + pp];
    }
    __syncthreads();

    float acc[8];
#pragma unroll
    for (int j = 0; j < 8; ++j) acc[j] = 0.f;

    const float* xrb = xr + (size_t)b * CC * HWSZ;

    for (int kk = 0; kk < 9; ++kk) {
        {
            const int ky = kk / 3, kx = kk - ky * 3;
            float w00, w01, w10, w11; int i00, i01, i10, i11;
            bilinear_params(offm[pixl][2 * kk], offm[pixl][2 * kk + 1],
                            offm[pixl][18 + kk], ho, wo, ky, kx,
                            w00, w01, w10, w11, i00, i01, i10, i11);
            const float* xg = xrb + (grp << 3) * HWSZ;
#pragma unroll
            for (int i = 0; i < 8; ++i) {
                const float* xc = xg + i * HWSZ;
                const float v = w00 * xc[i00] + w01 * xc[i01] +
                                w10 * xc[i10] + w11 * xc[i11];
                vtile[((grp << 3) + i) * 33 + pixl] = v;
            }
        }
        __syncthreads();

        const float* wk = wtd + (kk << 12) + (grp << 3);
#pragma unroll 8
        for (int c = 0; c < 64; ++c) {
            const float v = vtile[c * 33 + pixl];
            const float4* wr = (const float4*)(wk + (c << 6));
            const float4 w0 = wr[0];
            const float4 w1 = wr[1];
            acc[0] += v * w0.x; acc[1] += v * w0.y;
            acc[2] += v * w0.z; acc[3] += v * w0.w;
            acc[4] += v * w1.x; acc[5] += v * w1.y;
            acc[6] += v * w1.z; acc[7] += v * w1.w;
        }
        __syncthreads();
    }

#pragma unroll
    for (int q = 0; q < 8; ++q) {
        const int oc = (grp << 3) + q;
        out[((size_t)(b * OO + oc)) * HOWO + p0 + pixl] = acc[q] + bd[oc];
    }
}

// ---------------------------------------------------------------------------
// Slow fallback (round-0, verified)
// ---------------------------------------------------------------------------
__global__ __launch_bounds__(256) void conv_om_slow(
    const float* __restrict__ x, const float* __restrict__ w,
    const float* __restrict__ bias, float* __restrict__ off_out)
{
    const int xid = blockIdx.x;
    const int b   = xid >> 6;
    const int p   = ((xid & 63) << 8) + threadIdx.x;
    const int ho  = p >> 7, wo = p & 127;
    const int oc0 = blockIdx.y << 4;

    float acc[16];
#pragma unroll
    for (int j = 0; j < 16; ++j) {
        const int oc = oc0 + j;
        acc[j] = (oc < OMC) ? bias[oc] : 0.f;
    }
    const float* xb = x + (size_t)b * CC * HWSZ;
    for (int c = 0; c < CC; ++c) {
        const float* xc = xb + c * HWSZ;
        float t[9];
#pragma unroll
        for (int kh = 0; kh < 3; ++kh) {
            const int ih = ho + kh - 1;
            const bool rv = (unsigned)ih < (unsigned)HH;
#pragma unroll
            for (int kw = 0; kw < 3; ++kw) {
                const int iw = wo + kw - 1;
                t[kh * 3 + kw] =
                    (rv && (unsigned)iw < (unsigned)WW) ? xc[ih * WW + iw] : 0.f;
            }
        }
#pragma unroll
        for (int j = 0; j < 16; ++j) {
            const int oc = oc0 + j;
            if (oc < OMC) {
                const float* wj = w + (size_t)(oc * CC + c) * 9;
                float s = 0.f;
#pragma unroll
                for (int kk = 0; kk < 9; ++kk) s += t[kk] * wj[kk];
                acc[j] += s;
            }
        }
    }
#pragma unroll
    for (int j = 0; j < 16; ++j) {
        const int oc = oc0 + j;
        if (oc < 18) off_out[(b * 18 + oc) * HOWO + p] = acc[j];
    }
}

__global__ __launch_bounds__(256) void dcn_slow(
    const float* __restrict__ xr, const float* __restrict__ off,
    const float* __restrict__ wd, const float* __restrict__ bd,
    float* __restrict__ out, const float* __restrict__ xo,
    const float* __restrict__ wom, const float* __restrict__ bom)
{
    const int xid = blockIdx.x;
    const int b   = xid >> 6;
    const int p   = ((xid & 63) << 8) + threadIdx.x;
    const int ho  = p >> 7, wo = p & 127;
    const int o0  = blockIdx.y << 4;

    float acc[16];
#pragma unroll
    for (int j = 0; j < 16; ++j) acc[j] = bd[o0 + j];
    const float* xb = xr + (size_t)b * CC * HWSZ;

    for (int kk = 0; kk < 9; ++kk) {
        const float oy = off[(b * 18 + 2 * kk) * HOWO + p];
        const float ox = off[(b * 18 + 2 * kk + 1) * HOWO + p];
        float a = bom[18 + kk];
        const float* xob = xo + (size_t)b * CC * HWSZ;
        for (int c = 0; c < CC; ++c) {
            const float* xc2 = xob + c * HWSZ;
            const float* wj  = wom + (size_t)((18 + kk) * CC + c) * 9;
#pragma unroll
            for (int kh = 0; kh < 3; ++kh) {
                const int ih = ho + kh - 1;
                if ((unsigned)ih < (unsigned)HH) {
#pragma unroll
                    for (int kw = 0; kw < 3; ++kw) {
                        const int iw = wo + kw - 1;
                        if ((unsigned)iw < (unsigned)WW)
                            a += xc2[ih * WW + iw] * wj[kh * 3 + kw];
                    }
                }
            }
        }
        const float m = 1.f / (1.f + expf(-a));
        const int ky = kk / 3, kx = kk - ky * 3;
        float w00, w01, w10, w11; int i00, i01, i10, i11;
        bilinear_params(oy, ox, m, ho, wo, ky, kx,
                        w00, w01, w10, w11, i00, i01, i10, i11);
#pragma unroll 4
        for (int c = 0; c < CC; ++c) {
            const float* xc = xb + c * HWSZ;
            const float v = w00 * xc[i00] + w01 * xc[i01] +
                            w10 * xc[i10] + w11 * xc[i11];
#pragma unroll
            for (int j = 0; j < 16; ++j)
                acc[j] += v * wd[(size_t)((o0 + j) * CC + c) * 9 + kk];
        }
    }
#pragma unroll
    for (int j = 0; j < 16; ++j)
        out[((size_t)b * OO + o0 + j) * HOWO + p] = acc[j];
}

// ---------------------------------------------------------------------------
extern "C" void kernel_launch(void* const* d_in, const int* in_sizes, int n_in,
                              void* d_out, int out_size, void* d_ws, size_t ws_size,
                              hipStream_t stream)
{
    const float* x_off  = (const float*)d_in[0];
    const float* x_real = (const float*)d_in[1];
    const float* w_om   = (const float*)d_in[2];
    const float* b_om   = (const float*)d_in[3];
    const float* w_dcn  = (const float*)d_in[4];
    const float* b_dcn  = (const float*)d_in[5];

    float* out = (float*)d_out;
    const int outElems = BB * OO * HOWO;
    float* off_out = out + outElems;                  // [B][18][HoWo]

    // Full tier: xtr, xto (bf16 channels-last), Whi/Wlo, Womhi/Womlo
    const size_t xtB     = (size_t)BB * HWSZ * CC * 2;    // 4,194,304 each
    const size_t wSplitB = (size_t)64 * 576 * 2;          // 73,728 each
    const size_t womB    = (size_t)32 * 576 * 2;          // 36,864 each
    const size_t need_full = 2 * xtB + 2 * wSplitB + 2 * womB;   // 8,609,792

    const size_t wtDcnF = 9 * 64 * 64;
    const size_t wtOmF  = 9 * 64 * 28;
    const size_t need_mid = (wtDcnF + wtOmF + (size_t)BB * 9 * HOWO) * 4;

    if (ws_size >= need_full) {
        char* w = (char*)d_ws;
        ushortT* xtr   = (ushortT*)w;   w += xtB;
        ushortT* xto   = (ushortT*)w;   w += xtB;
        ushortT* Whi   = (ushortT*)w;   w += wSplitB;
        ushortT* Wlo   = (ushortT*)w;   w += wSplitB;
        ushortT* Womhi = (ushortT*)w;   w += womB;
        ushortT* Womlo = (ushortT*)w;

        hipLaunchKernelGGL(xtpose_prep, dim3(656), dim3(256), 0, stream,
                           x_real, x_off, xtr, xto, w_dcn, w_om,
                           Whi, Wlo, Womhi, Womlo);
        hipLaunchKernelGGL(fused_all, dim3(512), dim3(256), 0, stream,
                           xtr, xto, Womhi, Womlo, b_om, Whi, Wlo, b_dcn,
                           out, off_out);
    } else if (ws_size >= need_mid) {
        float* wtDcn   = (float*)d_ws;
        float* wtOm    = wtDcn + wtDcnF;
        float* maskBuf = wtOm + wtOmF;
        hipLaunchKernelGGL(prep_transpose, dim3(144), dim3(256), 0, stream,
                           w_dcn, w_om, wtDcn, wtOm);
        hipLaunchKernelGGL(conv_om2, dim3(128, 4), dim3(256), 0, stream,
                           x_off, wtOm, b_om, off_out, maskBuf);
        hipLaunchKernelGGL(dcn2, dim3(1024), dim3(256), 0, stream,
                           x_real, off_out, maskBuf, wtDcn, b_dcn, out);
    } else {
        hipLaunchKernelGGL(conv_om_slow, dim3(128, 2), dim3(256), 0, stream,
                           x_off, w_om, b_om, off_out);
        hipLaunchKernelGGL(dcn_slow, dim3(128, 4), dim3(256), 0, stream,
                           x_real, off_out, w_dcn, b_dcn, out,
                           x_off, w_om, b_om);
    }
}